// Round 1
// baseline (936.016 us; speedup 1.0000x reference)
//
#include <hip/hip_runtime.h>
#include <cstdint>
#include <cstddef>

#define A_TOTAL 261888
#define NBATCH  16
#define KTOP    1000
#define NBIN    16384
#define CAP     2048
#define NMS_T   0.7f

// level layout: H=W = 256,128,64,32,16 ; strides 4,8,16,32,64 ; sizes 32..512
__constant__ float c_stride[5] = {4.f, 8.f, 16.f, 32.f, 64.f};
// np.sqrt(float32(0.5)) = 0.707106769084930419921875
// np.sqrt(float32(2.0)) = 1.41421353816986083984375
// w = size / sqrt(ratio), h = size * sqrt(ratio), ratios (0.5, 1.0, 2.0)
__constant__ float c_aw[5][3] = {
  {(float)(32.0 /0.707106769084930419921875),  32.f, (float)(32.0 /1.41421353816986083984375)},
  {(float)(64.0 /0.707106769084930419921875),  64.f, (float)(64.0 /1.41421353816986083984375)},
  {(float)(128.0/0.707106769084930419921875), 128.f, (float)(128.0/1.41421353816986083984375)},
  {(float)(256.0/0.707106769084930419921875), 256.f, (float)(256.0/1.41421353816986083984375)},
  {(float)(512.0/0.707106769084930419921875), 512.f, (float)(512.0/1.41421353816986083984375)}};
__constant__ float c_ah[5][3] = {
  {(float)(32.0 *0.707106769084930419921875),  32.f, (float)(32.0 *1.41421353816986083984375)},
  {(float)(64.0 *0.707106769084930419921875),  64.f, (float)(64.0 *1.41421353816986083984375)},
  {(float)(128.0*0.707106769084930419921875), 128.f, (float)(128.0*1.41421353816986083984375)},
  {(float)(256.0*0.707106769084930419921875), 256.f, (float)(256.0*1.41421353816986083984375)},
  {(float)(512.0*0.707106769084930419921875), 512.f, (float)(512.0*1.41421353816986083984375)}};

__device__ __forceinline__ void decompA(int a, int& l, int& i) {
  if (a < 245760) {
    if (a < 196608) { l = 0; i = a; } else { l = 1; i = a - 196608; }
  } else if (a < 258048) { l = 2; i = a - 245760; }
  else if (a < 261120)   { l = 3; i = a - 258048; }
  else                   { l = 4; i = a - 261120; }
}

__device__ __forceinline__ float score_at(const float* c0, const float* c1,
                                          const float* c2, const float* c3,
                                          const float* c4, int b, int a) {
  int l, i; decompA(a, l, i);
  unsigned pix = (unsigned)i / 3u;
  int r = i - (int)pix * 3;
  int HW = 65536 >> (2 * l);
  const float* p = (l == 0) ? c0 : (l == 1) ? c1 : (l == 2) ? c2 : (l == 3) ? c3 : c4;
  float x = p[(size_t)(b * 3 + r) * HW + (int)pix];
  return 1.0f / (1.0f + expf(-x));
}

__device__ __forceinline__ int bin_of(float s) {
  int b = (int)(s * 16384.0f);
  return b > (NBIN - 1) ? (NBIN - 1) : (b < 0 ? 0 : b);
}

// ---------------- K0: zero output + histograms + counters ----------------
__global__ __launch_bounds__(256) void k_zero(float4* o, int n4, int* m, int nm) {
  int stride = gridDim.x * blockDim.x;
  int t = blockIdx.x * blockDim.x + threadIdx.x;
  float4 z = make_float4(0.f, 0.f, 0.f, 0.f);
  for (int i = t; i < n4; i += stride) o[i] = z;
  for (int i = t; i < nm; i += stride) m[i] = 0;
}

// ---------------- K1: sigmoid + histogram ----------------
__global__ __launch_bounds__(256) void k_hist(const float* c0, const float* c1,
                                              const float* c2, const float* c3,
                                              const float* c4, int* hist) {
  int b = blockIdx.y;
  int a = blockIdx.x * 256 + threadIdx.x;       // grid.x = 1023, A = 1023*256 exactly
  float s = score_at(c0, c1, c2, c3, c4, b, a);
  atomicAdd(&hist[b * NBIN + bin_of(s)], 1);
}

// ---------------- K2: find threshold bin per image ----------------
__global__ __launch_bounds__(256) void k_findbin(const int* hist, int* B0) {
  int b = blockIdx.x;
  __shared__ int csum[256];
  const int* h = hist + b * NBIN;
  int t = threadIdx.x;
  int s = 0;
  for (int i = 0; i < 64; i++) s += h[t * 64 + i];
  csum[t] = s;
  __syncthreads();
  if (t == 0) {
    int acc = 0, res = 0;
    for (int c = 255; c >= 0; c--) {
      if (acc + csum[c] >= KTOP) {
        int a2 = acc;
        int bin = c * 64 + 63;
        for (; bin > c * 64; bin--) { a2 += h[bin]; if (a2 >= KTOP) break; }
        if (bin == c * 64) { /* crossing happens at first bin of chunk */ }
        res = bin;
        break;
      }
      acc += csum[c];
    }
    B0[b] = res;
  }
}

// ---------------- K3: compact candidates >= threshold bin ----------------
__global__ __launch_bounds__(256) void k_compact(const float* c0, const float* c1,
                                                 const float* c2, const float* c3,
                                                 const float* c4, const int* B0,
                                                 int* cnt, unsigned long long* cand) {
  int b = blockIdx.y;
  int a = blockIdx.x * 256 + threadIdx.x;
  float s = score_at(c0, c1, c2, c3, c4, b, a);
  if (bin_of(s) >= B0[b]) {
    int pos = atomicAdd(&cnt[b], 1);
    if (pos < CAP) {
      unsigned key = __float_as_uint(s);
      cand[(size_t)b * CAP + pos] =
          ((unsigned long long)key << 32) | (unsigned)(~a);
    }
  }
}

// ---------------- K4: sort + decode + NMS + scatter write ----------------
__global__ __launch_bounds__(1024) void k_final(const float* b0, const float* b1,
                                                const float* b2, const float* b3,
                                                const float* b4,
                                                const unsigned long long* cand,
                                                const int* cnt,
                                                float* out5, float* keepo) {
  __shared__ unsigned long long sk[CAP];
  __shared__ float sx1[KTOP], sy1[KTOP], sx2[KTOP], sy2[KTOP], sar[KTOP];
  __shared__ float scx[KTOP], scy[KTOP], swd[KTOP], sht[KTOP], ssc[KTOP];
  __shared__ int ssup[1024];

  int b = blockIdx.x;
  int tid = threadIdx.x;
  int n = cnt[b]; if (n > CAP) n = CAP;

  // load candidates; skey = ~composite => ascending skey == (score desc, idx asc)
  for (int t = tid; t < CAP; t += 1024)
    sk[t] = (t < n) ? ~cand[(size_t)b * CAP + t] : ~0ull;
  __syncthreads();

  // bitonic sort ascending, N = 2048
  for (int k = 2; k <= CAP; k <<= 1) {
    for (int j = k >> 1; j > 0; j >>= 1) {
      for (int i = tid; i < CAP; i += 1024) {
        int ixj = i ^ j;
        if (ixj > i) {
          bool up = ((i & k) == 0);
          unsigned long long v0 = sk[i], v1 = sk[ixj];
          if ((v0 > v1) == up) { sk[i] = v1; sk[ixj] = v0; }
        }
      }
      __syncthreads();
    }
  }

  // decode top-1000
  if (tid < 1024) ssup[tid] = 1;
  if (tid < KTOP) {
    unsigned long long e = sk[tid];
    int a = (int)(unsigned)e;                 // low 32 bits = anchor index
    unsigned key = ~(unsigned)(e >> 32);
    float sc = __uint_as_float(key);
    int l, i; decompA(a, l, i);
    unsigned pix = (unsigned)i / 3u;
    int r = i - (int)pix * 3;
    int W = 256 >> l;
    int HW = 65536 >> (2 * l);
    int hh_i = (int)pix >> (8 - l);
    int ww_i = (int)pix & (W - 1);
    const float* bp = (l == 0) ? b0 : (l == 1) ? b1 : (l == 2) ? b2 : (l == 3) ? b3 : b4;
    size_t base = (size_t)(b * 12 + r * 4) * HW + (size_t)pix;
    float d0 = bp[base];
    float d1 = bp[base + HW];
    float d2 = bp[base + 2 * (size_t)HW];
    float d3 = bp[base + 3 * (size_t)HW];
    float stride = c_stride[l];
    float cxa = ((float)ww_i + 0.5f) * stride;
    float cya = ((float)hh_i + 0.5f) * stride;
    float aw = c_aw[l][r], ah = c_ah[l][r];
    float cx = cxa + d0 * aw;
    float cy = cya + d1 * ah;
    float wb = aw * expf(fminf(fmaxf(d2, -4.f), 4.f));
    float hb = ah * expf(fminf(fmaxf(d3, -4.f), 4.f));
    float x1 = cx - wb * 0.5f, x2 = cx + wb * 0.5f;
    float y1 = cy - hb * 0.5f, y2 = cy + hb * 0.5f;
    sx1[tid] = x1; sy1[tid] = y1; sx2[tid] = x2; sy2[tid] = y2;
    sar[tid] = (x2 - x1) * (y2 - y1);
    scx[tid] = cx; scy[tid] = cy; swd[tid] = wb; sht[tid] = hb; ssc[tid] = sc;
    ssup[tid] = 0;
  }
  __syncthreads();

  // chunked greedy NMS: 16 chunks of 64
  for (int c = 0; c < 16; c++) {
    int base = c * 64;
    if (tid < 64) {
      int j = base + tid;
      unsigned long long intra = 0;
      int sup;
      if (j < KTOP) {
        float x1 = sx1[j], y1 = sy1[j], x2 = sx2[j], y2 = sy2[j], ar = sar[j];
        for (int i2 = 0; i2 < 64; i2++) {
          int gi = base + i2;
          if (gi >= j) break;
          float iw = fminf(x2, sx2[gi]) - fmaxf(x1, sx1[gi]); iw = fmaxf(iw, 0.f);
          float ih = fminf(y2, sy2[gi]) - fmaxf(y1, sy1[gi]); ih = fmaxf(ih, 0.f);
          float inter = iw * ih;
          float iou = inter / (ar + sar[gi] - inter + 1e-6f);
          if (iou > NMS_T) intra |= (1ull << i2);
        }
        sup = ssup[j];
      } else {
        sup = 1;
      }
      // serial in-wave greedy over the 64 chunk boxes
      for (int i2 = 0; i2 < 64; i2++) {
        int si = __shfl(sup, i2, 64);
        if (!si && ((intra >> i2) & 1)) sup = 1;
      }
      if (j < KTOP) ssup[j] = sup;
    }
    __syncthreads();
    // apply chunk's kept boxes to all later boxes
    int j2 = base + 64 + tid;
    if (j2 < KTOP && !ssup[j2]) {
      float x1 = sx1[j2], y1 = sy1[j2], x2 = sx2[j2], y2 = sy2[j2], ar = sar[j2];
      for (int i2 = 0; i2 < 64; i2++) {
        int gi = base + i2;
        if (!ssup[gi]) {
          float iw = fminf(x2, sx2[gi]) - fmaxf(x1, sx1[gi]); iw = fmaxf(iw, 0.f);
          float ih = fminf(y2, sy2[gi]) - fmaxf(y1, sy1[gi]); ih = fmaxf(ih, 0.f);
          float inter = iw * ih;
          float iou = inter / (ar + sar[gi] - inter + 1e-6f);
          if (iou > NMS_T) { ssup[j2] = 1; break; }
        }
      }
    }
    __syncthreads();
  }

  // scatter outputs
  if (tid < KTOP && !ssup[tid]) {
    int a = (int)(unsigned)sk[tid];
    size_t p = (size_t)b * A_TOTAL + (size_t)a;
    size_t p5 = p * 5;
    out5[p5 + 0] = scx[tid];
    out5[p5 + 1] = scy[tid];
    out5[p5 + 2] = swd[tid];
    out5[p5 + 3] = sht[tid];
    out5[p5 + 4] = ssc[tid];
    keepo[p] = 1.0f;
  }
}

extern "C" void kernel_launch(void* const* d_in, const int* in_sizes, int n_in,
                              void* d_out, int out_size, void* d_ws, size_t ws_size,
                              hipStream_t stream) {
  const float *cls[5], *bbox[5];
  // setup_inputs() dict order is interleaved: cls_p2, bbox_p2, cls_p3, ...
  if (n_in >= 10 && in_sizes[1] == 4 * in_sizes[0]) {
    for (int l = 0; l < 5; l++) {
      cls[l]  = (const float*)d_in[2 * l];
      bbox[l] = (const float*)d_in[2 * l + 1];
    }
  } else {  // fallback: grouped (cls x5 then bbox x5, reference signature order)
    for (int l = 0; l < 5; l++) {
      cls[l]  = (const float*)d_in[l];
      bbox[l] = (const float*)d_in[5 + l];
    }
  }

  char* ws = (char*)d_ws;
  int* hist = (int*)ws;                                    // 16*16384*4 = 1,048,576 B
  int* cnt  = (int*)(ws + (size_t)NBATCH * NBIN * 4);      // 16*4 = 64 B (contiguous after hist)
  int* B0   = (int*)(ws + (size_t)NBATCH * NBIN * 4 + 64); // 64 B
  unsigned long long* cand =
      (unsigned long long*)(ws + (size_t)NBATCH * NBIN * 4 + 128); // 16*2048*8 = 262,144 B

  float* out5  = (float*)d_out;
  float* keepo = out5 + (size_t)NBATCH * A_TOTAL * 5;

  // zero: full output (B*A*6 fp32 = 6,285,312 float4) + hist + cnt (262,160 ints)
  k_zero<<<2048, 256, 0, stream>>>((float4*)d_out, (NBATCH * A_TOTAL * 6) / 4,
                                   hist, NBATCH * NBIN + NBATCH);

  dim3 g(A_TOTAL / 256, NBATCH);  // 1023 x 16, A is exactly 1023*256
  k_hist<<<g, 256, 0, stream>>>(cls[0], cls[1], cls[2], cls[3], cls[4], hist);
  k_findbin<<<NBATCH, 256, 0, stream>>>(hist, B0);
  k_compact<<<g, 256, 0, stream>>>(cls[0], cls[1], cls[2], cls[3], cls[4], B0, cnt, cand);
  k_final<<<NBATCH, 1024, 0, stream>>>(bbox[0], bbox[1], bbox[2], bbox[3], bbox[4],
                                       cand, cnt, out5, keepo);
}

// Round 2
// 550.126 us; speedup vs baseline: 1.7015x; 1.7015x over previous
//
#include <hip/hip_runtime.h>
#include <cstdint>
#include <cstddef>

#define A_TOTAL 261888
#define NBATCH  16
#define KTOP    1000
#define CAP     2048
#define NMS_T   0.7f

// ---- ws layout (bytes) ----
#define WS_COARSE 0                    // 16*256 ints  = 16384 B
#define WS_FINE   16384                // 16*64 ints   = 4096 B
#define WS_CSTAR  20480                // 16 ints
#define WS_SAB    20544                // 16 ints
#define WS_B0     20608                // 16 ints
#define WS_CNT    20672                // 16 ints
#define WS_CAND   20736                // 16*2048*8    = 262144 B
#define WS_IOUA   282880               // 16*1000*16   = 256000 B
#define WS_POUT   538880               // 16*1000*16   = 256000 B
#define WS_SOUT   794880               // 16*1000*4    = 64000 B
#define WS_AOUT   858880               // 16*1000*4    = 64000 B
#define WS_MASK   922880               // 16*1000*16*8 = 2048000 B
#define WS_NEED_FULL 2970880ull
#define N_ZERO_INTS 5184               // coarse+fine+cstar+sab+b0+cnt

__constant__ float c_stride[5] = {4.f, 8.f, 16.f, 32.f, 64.f};
__constant__ float c_aw[5][3] = {
  {(float)(32.0 /0.707106769084930419921875),  32.f, (float)(32.0 /1.41421353816986083984375)},
  {(float)(64.0 /0.707106769084930419921875),  64.f, (float)(64.0 /1.41421353816986083984375)},
  {(float)(128.0/0.707106769084930419921875), 128.f, (float)(128.0/1.41421353816986083984375)},
  {(float)(256.0/0.707106769084930419921875), 256.f, (float)(256.0/1.41421353816986083984375)},
  {(float)(512.0/0.707106769084930419921875), 512.f, (float)(512.0/1.41421353816986083984375)}};
__constant__ float c_ah[5][3] = {
  {(float)(32.0 *0.707106769084930419921875),  32.f, (float)(32.0 *1.41421353816986083984375)},
  {(float)(64.0 *0.707106769084930419921875),  64.f, (float)(64.0 *1.41421353816986083984375)},
  {(float)(128.0*0.707106769084930419921875), 128.f, (float)(128.0*1.41421353816986083984375)},
  {(float)(256.0*0.707106769084930419921875), 256.f, (float)(256.0*1.41421353816986083984375)},
  {(float)(512.0*0.707106769084930419921875), 512.f, (float)(512.0*1.41421353816986083984375)}};

__device__ __forceinline__ void decompA(int a, int& l, int& i) {
  if (a < 245760) {
    if (a < 196608) { l = 0; i = a; } else { l = 1; i = a - 196608; }
  } else if (a < 258048) { l = 2; i = a - 245760; }
  else if (a < 261120)   { l = 3; i = a - 258048; }
  else                   { l = 4; i = a - 261120; }
}

__device__ __forceinline__ float score_at(const float* c0, const float* c1,
                                          const float* c2, const float* c3,
                                          const float* c4, int b, int a) {
  int l, i; decompA(a, l, i);
  unsigned pix = (unsigned)i / 3u;
  int r = i - (int)pix * 3;
  int HW = 65536 >> (2 * l);
  const float* p = (l == 0) ? c0 : (l == 1) ? c1 : (l == 2) ? c2 : (l == 3) ? c3 : c4;
  float x = p[(size_t)(b * 3 + r) * HW + (int)pix];
  return 1.0f / (1.0f + expf(-x));
}

__device__ __forceinline__ int bin_of(float s) {
  int b = (int)(s * 16384.0f);
  return b > 16383 ? 16383 : (b < 0 ? 0 : b);
}

// decode anchor a with deltas -> box; returns via refs
__device__ __forceinline__ void decode_box(const float* b0p, const float* b1p,
                                           const float* b2p, const float* b3p,
                                           const float* b4p, int b, int a,
                                           float& x1, float& y1, float& x2, float& y2,
                                           float& cx, float& cy, float& wb, float& hb) {
  int l, i; decompA(a, l, i);
  unsigned pix = (unsigned)i / 3u;
  int r = i - (int)pix * 3;
  int W = 256 >> l;
  int HW = 65536 >> (2 * l);
  int hh_i = (int)pix >> (8 - l);
  int ww_i = (int)pix & (W - 1);
  const float* bp = (l == 0) ? b0p : (l == 1) ? b1p : (l == 2) ? b2p : (l == 3) ? b3p : b4p;
  size_t base = (size_t)(b * 12 + r * 4) * HW + (size_t)pix;
  float d0 = bp[base];
  float d1 = bp[base + HW];
  float d2 = bp[base + 2 * (size_t)HW];
  float d3 = bp[base + 3 * (size_t)HW];
  float stride = c_stride[l];
  float cxa = ((float)ww_i + 0.5f) * stride;
  float cya = ((float)hh_i + 0.5f) * stride;
  float aw = c_aw[l][r], ah = c_ah[l][r];
  cx = cxa + d0 * aw;
  cy = cya + d1 * ah;
  wb = aw * expf(fminf(fmaxf(d2, -4.f), 4.f));
  hb = ah * expf(fminf(fmaxf(d3, -4.f), 4.f));
  x1 = cx - wb * 0.5f; x2 = cx + wb * 0.5f;
  y1 = cy - hb * 0.5f; y2 = cy + hb * 0.5f;
}

// ---------------- K0: zero output + counter region ----------------
__global__ __launch_bounds__(256) void k_zero(float4* o, int n4, int* m, int nm) {
  int stride = gridDim.x * blockDim.x;
  int t = blockIdx.x * blockDim.x + threadIdx.x;
  float4 z = make_float4(0.f, 0.f, 0.f, 0.f);
  for (int i = t; i < n4; i += stride) o[i] = z;
  for (int i = t; i < nm; i += stride) m[i] = 0;
}

// ---------------- K1: coarse histogram (256 bins, LDS-privatized) ----------------
__global__ __launch_bounds__(1024) void k_hist1(const float* c0, const float* c1,
                                                const float* c2, const float* c3,
                                                const float* c4, int* coarse) {
  __shared__ int lh[256];
  int b = blockIdx.y;
  int tid = threadIdx.x;
  if (tid < 256) lh[tid] = 0;
  __syncthreads();
  int base = blockIdx.x * 32736;
  for (int it = 0; it < 32; it++) {
    int idx = it * 1024 + tid;
    if (idx < 32736) {
      float s = score_at(c0, c1, c2, c3, c4, b, base + idx);
      atomicAdd(&lh[bin_of(s) >> 6], 1);
    }
  }
  __syncthreads();
  if (tid < 256) {
    int v = lh[tid];
    if (v) atomicAdd(&coarse[b * 256 + tid], v);
  }
}

// ---------------- K2: find coarse crossing bin ----------------
__global__ __launch_bounds__(256) void k_scan1(const int* coarse, int* cstar, int* sab) {
  __shared__ int ch[256];
  int b = blockIdx.x;
  int t = threadIdx.x;
  ch[t] = coarse[b * 256 + t];
  __syncthreads();
  if (t == 0) {
    int acc = 0, cs = 0, s = 0;
    for (int cb = 255; cb >= 0; cb--) {
      if (acc + ch[cb] >= KTOP) { cs = cb; s = acc; break; }
      acc += ch[cb];
    }
    cstar[b] = cs;
    sab[b] = s;
  }
}

// ---------------- K3: fine histogram within crossing coarse bin ----------------
__global__ __launch_bounds__(1024) void k_hist2(const float* c0, const float* c1,
                                                const float* c2, const float* c3,
                                                const float* c4, const int* cstar,
                                                int* fine) {
  int b = blockIdx.y;
  int tid = threadIdx.x;
  int cs = cstar[b];
  int base = blockIdx.x * 32736;
  for (int it = 0; it < 32; it++) {
    int idx = it * 1024 + tid;
    if (idx < 32736) {
      float s = score_at(c0, c1, c2, c3, c4, b, base + idx);
      int bin = bin_of(s);
      if ((bin >> 6) == cs) atomicAdd(&fine[b * 64 + (bin & 63)], 1);
    }
  }
}

// ---------------- K4: find exact fine threshold bin ----------------
__global__ __launch_bounds__(64) void k_scan2(const int* fine, const int* cstar,
                                              const int* sab, int* b0out) {
  __shared__ int fh[64];
  int b = blockIdx.x;
  int t = threadIdx.x;
  fh[t] = fine[b * 64 + t];
  __syncthreads();
  if (t == 0) {
    int acc = sab[b];
    int res = cstar[b] * 64;
    for (int f = 63; f >= 0; f--) {
      acc += fh[f];
      if (acc >= KTOP) { res = cstar[b] * 64 + f; break; }
    }
    b0out[b] = res;
  }
}

// ---------------- K5: compact candidates >= threshold bin ----------------
// key = (~score_bits << 32) | anchor : ascending = (score desc, idx asc)
__global__ __launch_bounds__(1024) void k_compact(const float* c0, const float* c1,
                                                  const float* c2, const float* c3,
                                                  const float* c4, const int* b0in,
                                                  int* cnt, unsigned long long* cand) {
  int b = blockIdx.y;
  int tid = threadIdx.x;
  int B0v = b0in[b];
  int base = blockIdx.x * 32736;
  for (int it = 0; it < 32; it++) {
    int idx = it * 1024 + tid;
    if (idx < 32736) {
      int a = base + idx;
      float s = score_at(c0, c1, c2, c3, c4, b, a);
      if (bin_of(s) >= B0v) {
        int pos = atomicAdd(&cnt[b], 1);
        if (pos < CAP) {
          unsigned key = ~__float_as_uint(s);
          cand[(size_t)b * CAP + pos] = ((unsigned long long)key << 32) | (unsigned)a;
        }
      }
    }
  }
}

// ---------------- K6: rank-by-count + decode into rank-ordered arrays ----------------
__global__ __launch_bounds__(1024) void k_rank(const float* b0p, const float* b1p,
                                               const float* b2p, const float* b3p,
                                               const float* b4p,
                                               const unsigned long long* cand,
                                               const int* cnt,
                                               float4* iouA, float4* pout,
                                               float* sout, int* aout) {
  __shared__ unsigned long long sk[CAP];
  int b = blockIdx.x;
  int tid = threadIdx.x;
  int n = cnt[b]; if (n > CAP) n = CAP;
  for (int t = tid; t < CAP; t += 1024)
    sk[t] = (t < n) ? cand[(size_t)b * CAP + t] : ~0ull;
  __syncthreads();
  unsigned long long my0 = sk[tid], my1 = sk[tid + 1024];
  int r0 = 0, r1 = 0;
  #pragma unroll 4
  for (int j = 0; j < n; j++) {
    unsigned long long k = sk[j];
    r0 += (k < my0) ? 1 : 0;
    r1 += (k < my1) ? 1 : 0;
  }
  for (int pass = 0; pass < 2; pass++) {
    int slot = tid + pass * 1024;
    int r = pass == 0 ? r0 : r1;
    unsigned long long e = pass == 0 ? my0 : my1;
    if (slot < n && r < KTOP) {
      int a = (int)(unsigned)e;
      float sc = __uint_as_float(~(unsigned)(e >> 32));
      float x1, y1, x2, y2, cx, cy, wb, hb;
      decode_box(b0p, b1p, b2p, b3p, b4p, b, a, x1, y1, x2, y2, cx, cy, wb, hb);
      int o = b * KTOP + r;
      iouA[o] = make_float4(x1, y1, x2, y2);
      pout[o] = make_float4(cx, cy, wb, hb);
      sout[o] = sc;
      aout[o] = a;
    }
  }
}

// ---------------- K7: IoU bit-matrix (256 blocks) ----------------
// mask[b][row][cc] bit c set iff col=cc*64+c > row, col<1000, IoU>thr
__global__ __launch_bounds__(1024) void k_iou(const float4* iouA,
                                              unsigned long long* gmask) {
  __shared__ float4 bx[KTOP];
  int b = blockIdx.y;
  int tid = threadIdx.x;
  if (tid < KTOP) bx[tid] = iouA[b * KTOP + tid];
  __syncthreads();
  int row = blockIdx.x * 64 + (tid >> 4);
  int cc = tid & 15;
  if (row >= KTOP) return;
  float4 rb = bx[row];
  float rar = (rb.z - rb.x) * (rb.w - rb.y);
  unsigned long long bits = 0;
  int cbase = cc * 64;
  #pragma unroll 4
  for (int c = 0; c < 64; c++) {
    int col = cbase + c;
    if (col < KTOP && col > row) {
      float4 cb4 = bx[col];
      float iw = fminf(rb.z, cb4.z) - fmaxf(rb.x, cb4.x); iw = fmaxf(iw, 0.f);
      float ih = fminf(rb.w, cb4.w) - fmaxf(rb.y, cb4.y); ih = fmaxf(ih, 0.f);
      float inter = iw * ih;
      float car = (cb4.z - cb4.x) * (cb4.w - cb4.y);
      float iou = inter / (rar + car - inter + 1e-6f);
      if (iou > NMS_T) bits |= (1ull << c);
    }
  }
  gmask[((size_t)b * KTOP + row) * 16 + cc] = bits;
}

// ---------------- K8: greedy resolve over bitmask rows + scatter write ----------------
__global__ __launch_bounds__(1024) void k_greedy(const unsigned long long* gmask,
                                                 const float4* pout, const float* sout,
                                                 const int* aout,
                                                 float* out5, float* keepo) {
  __shared__ unsigned long long mrow[500 * 16];
  __shared__ unsigned long long kw[16];
  int b = blockIdx.x;
  int tid = threadIdx.x;
  unsigned long long rem = 0;
  int lane = tid & 63;
  // phase 0: rows 0..499
  for (int t = tid; t < 8000; t += 1024) mrow[t] = gmask[(size_t)b * 16000 + t];
  __syncthreads();
  if (tid < 64) {
    for (int i = 0; i < 500; i++) {
      unsigned long long rw = __shfl(rem, i >> 6, 64);
      if (!((rw >> (i & 63)) & 1) && lane < 16) rem |= mrow[i * 16 + lane];
    }
  }
  __syncthreads();
  // phase 1: rows 500..999
  for (int t = tid; t < 8000; t += 1024) mrow[t] = gmask[(size_t)b * 16000 + 8000 + t];
  __syncthreads();
  if (tid < 64) {
    for (int i = 500; i < KTOP; i++) {
      unsigned long long rw = __shfl(rem, i >> 6, 64);
      if (!((rw >> (i & 63)) & 1) && lane < 16) rem |= mrow[(i - 500) * 16 + lane];
    }
    if (lane < 16) kw[lane] = rem;
  }
  __syncthreads();
  if (tid < KTOP && !((kw[tid >> 6] >> (tid & 63)) & 1)) {
    int o = b * KTOP + tid;
    float4 pq = pout[o];
    float sc = sout[o];
    int a = aout[o];
    size_t p = (size_t)b * A_TOTAL + (size_t)a;
    float* op = out5 + p * 5;
    op[0] = pq.x; op[1] = pq.y; op[2] = pq.z; op[3] = pq.w; op[4] = sc;
    keepo[p] = 1.0f;
  }
}

// ---------------- fallback: round-1 monolithic sort+NMS (proven correct) ----------------
__global__ __launch_bounds__(1024) void k_final_fb(const float* b0p, const float* b1p,
                                                   const float* b2p, const float* b3p,
                                                   const float* b4p,
                                                   const unsigned long long* cand,
                                                   const int* cnt,
                                                   float* out5, float* keepo) {
  __shared__ unsigned long long sk[CAP];
  __shared__ float sx1[KTOP], sy1[KTOP], sx2[KTOP], sy2[KTOP], sar[KTOP];
  __shared__ float scx[KTOP], scy[KTOP], swd[KTOP], sht[KTOP], ssc[KTOP];
  __shared__ int ssup[1024];
  int b = blockIdx.x;
  int tid = threadIdx.x;
  int n = cnt[b]; if (n > CAP) n = CAP;
  for (int t = tid; t < CAP; t += 1024)
    sk[t] = (t < n) ? cand[(size_t)b * CAP + t] : ~0ull;
  __syncthreads();
  for (int k = 2; k <= CAP; k <<= 1) {
    for (int j = k >> 1; j > 0; j >>= 1) {
      for (int i = tid; i < CAP; i += 1024) {
        int ixj = i ^ j;
        if (ixj > i) {
          bool up = ((i & k) == 0);
          unsigned long long v0 = sk[i], v1 = sk[ixj];
          if ((v0 > v1) == up) { sk[i] = v1; sk[ixj] = v0; }
        }
      }
      __syncthreads();
    }
  }
  if (tid < 1024) ssup[tid] = 1;
  if (tid < KTOP) {
    unsigned long long e = sk[tid];
    int a = (int)(unsigned)e;
    float sc = __uint_as_float(~(unsigned)(e >> 32));
    float x1, y1, x2, y2, cx, cy, wb, hb;
    decode_box(b0p, b1p, b2p, b3p, b4p, b, a, x1, y1, x2, y2, cx, cy, wb, hb);
    sx1[tid] = x1; sy1[tid] = y1; sx2[tid] = x2; sy2[tid] = y2;
    sar[tid] = (x2 - x1) * (y2 - y1);
    scx[tid] = cx; scy[tid] = cy; swd[tid] = wb; sht[tid] = hb; ssc[tid] = sc;
    ssup[tid] = 0;
  }
  __syncthreads();
  for (int c = 0; c < 16; c++) {
    int base = c * 64;
    if (tid < 64) {
      int j = base + tid;
      unsigned long long intra = 0;
      int sup;
      if (j < KTOP) {
        float x1 = sx1[j], y1 = sy1[j], x2 = sx2[j], y2 = sy2[j], ar = sar[j];
        for (int i2 = 0; i2 < 64; i2++) {
          int gi = base + i2;
          if (gi >= j) break;
          float iw = fminf(x2, sx2[gi]) - fmaxf(x1, sx1[gi]); iw = fmaxf(iw, 0.f);
          float ih = fminf(y2, sy2[gi]) - fmaxf(y1, sy1[gi]); ih = fmaxf(ih, 0.f);
          float inter = iw * ih;
          float iou = inter / (ar + sar[gi] - inter + 1e-6f);
          if (iou > NMS_T) intra |= (1ull << i2);
        }
        sup = ssup[j];
      } else sup = 1;
      for (int i2 = 0; i2 < 64; i2++) {
        int si = __shfl(sup, i2, 64);
        if (!si && ((intra >> i2) & 1)) sup = 1;
      }
      if (j < KTOP) ssup[j] = sup;
    }
    __syncthreads();
    int j2 = base + 64 + tid;
    if (j2 < KTOP && !ssup[j2]) {
      float x1 = sx1[j2], y1 = sy1[j2], x2 = sx2[j2], y2 = sy2[j2], ar = sar[j2];
      for (int i2 = 0; i2 < 64; i2++) {
        int gi = base + i2;
        if (!ssup[gi]) {
          float iw = fminf(x2, sx2[gi]) - fmaxf(x1, sx1[gi]); iw = fmaxf(iw, 0.f);
          float ih = fminf(y2, sy2[gi]) - fmaxf(y1, sy1[gi]); ih = fmaxf(ih, 0.f);
          float inter = iw * ih;
          float iou = inter / (ar + sar[gi] - inter + 1e-6f);
          if (iou > NMS_T) { ssup[j2] = 1; break; }
        }
      }
    }
    __syncthreads();
  }
  if (tid < KTOP && !ssup[tid]) {
    int a = (int)(unsigned)sk[tid];
    size_t p = (size_t)b * A_TOTAL + (size_t)a;
    size_t p5 = p * 5;
    out5[p5 + 0] = scx[tid];
    out5[p5 + 1] = scy[tid];
    out5[p5 + 2] = swd[tid];
    out5[p5 + 3] = sht[tid];
    out5[p5 + 4] = ssc[tid];
    keepo[p] = 1.0f;
  }
}

extern "C" void kernel_launch(void* const* d_in, const int* in_sizes, int n_in,
                              void* d_out, int out_size, void* d_ws, size_t ws_size,
                              hipStream_t stream) {
  const float *cls[5], *bbox[5];
  if (n_in >= 10 && in_sizes[1] == 4 * in_sizes[0]) {       // interleaved dict order
    for (int l = 0; l < 5; l++) { cls[l] = (const float*)d_in[2*l]; bbox[l] = (const float*)d_in[2*l+1]; }
  } else {                                                   // grouped order
    for (int l = 0; l < 5; l++) { cls[l] = (const float*)d_in[l]; bbox[l] = (const float*)d_in[5+l]; }
  }

  char* ws = (char*)d_ws;
  int* coarse = (int*)(ws + WS_COARSE);
  int* fine   = (int*)(ws + WS_FINE);
  int* cstar  = (int*)(ws + WS_CSTAR);
  int* sab    = (int*)(ws + WS_SAB);
  int* b0w    = (int*)(ws + WS_B0);
  int* cnt    = (int*)(ws + WS_CNT);
  unsigned long long* cand = (unsigned long long*)(ws + WS_CAND);
  float4* iouA = (float4*)(ws + WS_IOUA);
  float4* pout = (float4*)(ws + WS_POUT);
  float*  sout = (float*)(ws + WS_SOUT);
  int*    aout = (int*)(ws + WS_AOUT);
  unsigned long long* gmask = (unsigned long long*)(ws + WS_MASK);

  float* out5  = (float*)d_out;
  float* keepo = out5 + (size_t)NBATCH * A_TOTAL * 5;

  k_zero<<<4096, 256, 0, stream>>>((float4*)d_out, (NBATCH * A_TOTAL * 6) / 4,
                                   (int*)ws, N_ZERO_INTS);

  dim3 g8(8, NBATCH);   // 8 blocks x 32736 anchors = 261888
  k_hist1<<<g8, 1024, 0, stream>>>(cls[0], cls[1], cls[2], cls[3], cls[4], coarse);
  k_scan1<<<NBATCH, 256, 0, stream>>>(coarse, cstar, sab);
  k_hist2<<<g8, 1024, 0, stream>>>(cls[0], cls[1], cls[2], cls[3], cls[4], cstar, fine);
  k_scan2<<<NBATCH, 64, 0, stream>>>(fine, cstar, sab, b0w);
  k_compact<<<g8, 1024, 0, stream>>>(cls[0], cls[1], cls[2], cls[3], cls[4], b0w, cnt, cand);

  if (ws_size >= WS_NEED_FULL) {
    k_rank<<<NBATCH, 1024, 0, stream>>>(bbox[0], bbox[1], bbox[2], bbox[3], bbox[4],
                                        cand, cnt, iouA, pout, sout, aout);
    dim3 gi(16, NBATCH);  // 16 row-chunks x 16 images
    k_iou<<<gi, 1024, 0, stream>>>(iouA, gmask);
    k_greedy<<<NBATCH, 1024, 0, stream>>>(gmask, pout, sout, aout, out5, keepo);
  } else {
    k_final_fb<<<NBATCH, 1024, 0, stream>>>(bbox[0], bbox[1], bbox[2], bbox[3], bbox[4],
                                            cand, cnt, out5, keepo);
  }
}

// Round 3
// 519.158 us; speedup vs baseline: 1.8030x; 1.0596x over previous
//
#include <hip/hip_runtime.h>
#include <cstdint>
#include <cstddef>

#define A_TOTAL 261888
#define NBATCH  16
#define KTOP    1000
#define CAP     2048
#define NMS_T   0.7f
#define F4_PER_IMG 65472          // 261888/4

// ---- ws layout (bytes) ----
#define WS_COARSE 0                    // 16*256 ints  = 16384 B
#define WS_FINE   16384                // 16*64 ints   = 4096 B
#define WS_CSTAR  20480                // 16 ints
#define WS_SAB    20544                // 16 ints
#define WS_B0     20608                // 16 ints
#define WS_CNT    20672                // 16 ints
#define WS_CAND   20736                // 16*2048*8    = 262144 B
#define WS_IOUA   282880               // 16*1000*16   = 256000 B
#define WS_POUT   538880               // 16*1000*16   = 256000 B
#define WS_SOUT   794880               // 16*1000*4    = 64000 B
#define WS_AOUT   858880               // 16*1000*4    = 64000 B
#define WS_MASK   922880               // 16*1000*16*8 = 2048000 B
#define WS_SCORES 2970880              // 16*261888*4  = 16760832 B
#define WS_NEED_FULL   2970880ull
#define WS_NEED_SCORES 19731712ull
#define N_ZERO_INTS 5184               // coarse+fine+cstar+sab+b0+cnt

__constant__ float c_stride[5] = {4.f, 8.f, 16.f, 32.f, 64.f};
__constant__ float c_aw[5][3] = {
  {(float)(32.0 /0.707106769084930419921875),  32.f, (float)(32.0 /1.41421353816986083984375)},
  {(float)(64.0 /0.707106769084930419921875),  64.f, (float)(64.0 /1.41421353816986083984375)},
  {(float)(128.0/0.707106769084930419921875), 128.f, (float)(128.0/1.41421353816986083984375)},
  {(float)(256.0/0.707106769084930419921875), 256.f, (float)(256.0/1.41421353816986083984375)},
  {(float)(512.0/0.707106769084930419921875), 512.f, (float)(512.0/1.41421353816986083984375)}};
__constant__ float c_ah[5][3] = {
  {(float)(32.0 *0.707106769084930419921875),  32.f, (float)(32.0 *1.41421353816986083984375)},
  {(float)(64.0 *0.707106769084930419921875),  64.f, (float)(64.0 *1.41421353816986083984375)},
  {(float)(128.0*0.707106769084930419921875), 128.f, (float)(128.0*1.41421353816986083984375)},
  {(float)(256.0*0.707106769084930419921875), 256.f, (float)(256.0*1.41421353816986083984375)},
  {(float)(512.0*0.707106769084930419921875), 512.f, (float)(512.0*1.41421353816986083984375)}};

__device__ __forceinline__ void decompA(int a, int& l, int& i) {
  if (a < 245760) {
    if (a < 196608) { l = 0; i = a; } else { l = 1; i = a - 196608; }
  } else if (a < 258048) { l = 2; i = a - 245760; }
  else if (a < 261120)   { l = 3; i = a - 258048; }
  else                   { l = 4; i = a - 261120; }
}

// element position e in per-image layout [level][r][pix] -> level & within-level offset
__device__ __forceinline__ void decompE(int e, int& l, int& el) {
  if (e < 245760) {
    if (e < 196608) { l = 0; el = e; } else { l = 1; el = e - 196608; }
  } else if (e < 258048) { l = 2; el = e - 245760; }
  else if (e < 261120)   { l = 3; el = e - 258048; }
  else                   { l = 4; el = e - 261120; }
}

__device__ __forceinline__ float score_at(const float* c0, const float* c1,
                                          const float* c2, const float* c3,
                                          const float* c4, int b, int a) {
  int l, i; decompA(a, l, i);
  unsigned pix = (unsigned)i / 3u;
  int r = i - (int)pix * 3;
  int HW = 65536 >> (2 * l);
  const float* p = (l == 0) ? c0 : (l == 1) ? c1 : (l == 2) ? c2 : (l == 3) ? c3 : c4;
  float x = p[(size_t)(b * 3 + r) * HW + (int)pix];
  return 1.0f / (1.0f + expf(-x));
}

__device__ __forceinline__ int bin_of(float s) {
  int b = (int)(s * 16384.0f);
  return b > 16383 ? 16383 : (b < 0 ? 0 : b);
}

__device__ __forceinline__ void decode_box(const float* b0p, const float* b1p,
                                           const float* b2p, const float* b3p,
                                           const float* b4p, int b, int a,
                                           float& x1, float& y1, float& x2, float& y2,
                                           float& cx, float& cy, float& wb, float& hb) {
  int l, i; decompA(a, l, i);
  unsigned pix = (unsigned)i / 3u;
  int r = i - (int)pix * 3;
  int W = 256 >> l;
  int HW = 65536 >> (2 * l);
  int hh_i = (int)pix >> (8 - l);
  int ww_i = (int)pix & (W - 1);
  const float* bp = (l == 0) ? b0p : (l == 1) ? b1p : (l == 2) ? b2p : (l == 3) ? b3p : b4p;
  size_t base = (size_t)(b * 12 + r * 4) * HW + (size_t)pix;
  float d0 = bp[base];
  float d1 = bp[base + HW];
  float d2 = bp[base + 2 * (size_t)HW];
  float d3 = bp[base + 3 * (size_t)HW];
  float stride = c_stride[l];
  float cxa = ((float)ww_i + 0.5f) * stride;
  float cya = ((float)hh_i + 0.5f) * stride;
  float aw = c_aw[l][r], ah = c_ah[l][r];
  cx = cxa + d0 * aw;
  cy = cya + d1 * ah;
  wb = aw * expf(fminf(fmaxf(d2, -4.f), 4.f));
  hb = ah * expf(fminf(fmaxf(d3, -4.f), 4.f));
  x1 = cx - wb * 0.5f; x2 = cx + wb * 0.5f;
  y1 = cy - hb * 0.5f; y2 = cy + hb * 0.5f;
}

// ---------------- K0: zero output + counter region ----------------
__global__ __launch_bounds__(256) void k_zero(float4* o, int n4, int* m, int nm) {
  int stride = gridDim.x * blockDim.x;
  int t = blockIdx.x * blockDim.x + threadIdx.x;
  float4 z = make_float4(0.f, 0.f, 0.f, 0.f);
  for (int i = t; i < n4; i += stride) o[i] = z;
  for (int i = t; i < nm; i += stride) m[i] = 0;
}

// ---------------- K1: layout-order sigmoid + score buffer + coarse hist ----------------
__global__ __launch_bounds__(256) void k_score(const float* c0, const float* c1,
                                               const float* c2, const float* c3,
                                               const float* c4,
                                               float4* sbuf, int* coarse) {
  __shared__ int lh[256];
  int b = blockIdx.y;
  int tid = threadIdx.x;
  lh[tid] = 0;
  __syncthreads();
  for (int f = blockIdx.x * 256 + tid; f < F4_PER_IMG; f += gridDim.x * 256) {
    int l, off4;
    if (f < 49152) { l = 0; off4 = f; }
    else if (f < 61440) { l = 1; off4 = f - 49152; }
    else if (f < 64512) { l = 2; off4 = f - 61440; }
    else if (f < 65280) { l = 3; off4 = f - 64512; }
    else { l = 4; off4 = f - 65280; }
    int HW4x3 = 3 * (16384 >> (2 * l));  // 3*HW/4
    const float4* p = (const float4*)((l == 0) ? c0 : (l == 1) ? c1 : (l == 2) ? c2
                                       : (l == 3) ? c3 : c4);
    float4 x = p[(size_t)b * HW4x3 + off4];
    float4 s;
    s.x = 1.0f / (1.0f + expf(-x.x));
    s.y = 1.0f / (1.0f + expf(-x.y));
    s.z = 1.0f / (1.0f + expf(-x.z));
    s.w = 1.0f / (1.0f + expf(-x.w));
    sbuf[(size_t)b * F4_PER_IMG + f] = s;
    atomicAdd(&lh[bin_of(s.x) >> 6], 1);
    atomicAdd(&lh[bin_of(s.y) >> 6], 1);
    atomicAdd(&lh[bin_of(s.z) >> 6], 1);
    atomicAdd(&lh[bin_of(s.w) >> 6], 1);
  }
  __syncthreads();
  int v = lh[tid];
  if (v) atomicAdd(&coarse[b * 256 + tid], v);
}

// ---------------- K2: find coarse crossing bin ----------------
__global__ __launch_bounds__(256) void k_scan1(const int* coarse, int* cstar, int* sab) {
  __shared__ int ch[256];
  int b = blockIdx.x;
  int t = threadIdx.x;
  ch[t] = coarse[b * 256 + t];
  __syncthreads();
  if (t == 0) {
    int acc = 0, cs = 0, s = 0;
    for (int cb = 255; cb >= 0; cb--) {
      if (acc + ch[cb] >= KTOP) { cs = cb; s = acc; break; }
      acc += ch[cb];
    }
    cstar[b] = cs;
    sab[b] = s;
  }
}

// ---------------- K3: fine histogram from score buffer ----------------
__global__ __launch_bounds__(256) void k_fine(const float4* sbuf, const int* cstar,
                                              int* fine) {
  int b = blockIdx.y;
  int cs = cstar[b];
  for (int f = blockIdx.x * 256 + threadIdx.x; f < F4_PER_IMG; f += gridDim.x * 256) {
    float4 s = sbuf[(size_t)b * F4_PER_IMG + f];
    int b0 = bin_of(s.x), b1 = bin_of(s.y), b2 = bin_of(s.z), b3 = bin_of(s.w);
    if ((b0 >> 6) == cs) atomicAdd(&fine[b * 64 + (b0 & 63)], 1);
    if ((b1 >> 6) == cs) atomicAdd(&fine[b * 64 + (b1 & 63)], 1);
    if ((b2 >> 6) == cs) atomicAdd(&fine[b * 64 + (b2 & 63)], 1);
    if ((b3 >> 6) == cs) atomicAdd(&fine[b * 64 + (b3 & 63)], 1);
  }
}

// ---------------- K4: find exact fine threshold bin ----------------
__global__ __launch_bounds__(64) void k_scan2(const int* fine, const int* cstar,
                                              const int* sab, int* b0out) {
  __shared__ int fh[64];
  int b = blockIdx.x;
  int t = threadIdx.x;
  fh[t] = fine[b * 64 + t];
  __syncthreads();
  if (t == 0) {
    int acc = sab[b];
    int res = cstar[b] * 64;
    for (int f = 63; f >= 0; f--) {
      acc += fh[f];
      if (acc >= KTOP) { res = cstar[b] * 64 + f; break; }
    }
    b0out[b] = res;
  }
}

// ---------------- K5: compact candidates from score buffer ----------------
// key = (~score_bits << 32) | anchor : ascending = (score desc, idx asc)
__global__ __launch_bounds__(256) void k_compact(const float4* sbuf, const int* b0in,
                                                 int* cnt, unsigned long long* cand) {
  int b = blockIdx.y;
  int B0v = b0in[b];
  for (int f = blockIdx.x * 256 + threadIdx.x; f < F4_PER_IMG; f += gridDim.x * 256) {
    float4 s = sbuf[(size_t)b * F4_PER_IMG + f];
    float sv[4] = {s.x, s.y, s.z, s.w};
    #pragma unroll
    for (int j = 0; j < 4; j++) {
      if (bin_of(sv[j]) >= B0v) {
        int e = f * 4 + j;
        int l, el; decompE(e, l, el);
        int shift = 16 - 2 * l;
        int r = el >> shift;
        int pix = el & ((1 << shift) - 1);
        int lbase = e - el;                 // level anchor base == element base
        int a = lbase + pix * 3 + r;
        int pos = atomicAdd(&cnt[b], 1);
        if (pos < CAP) {
          unsigned key = ~__float_as_uint(sv[j]);
          cand[(size_t)b * CAP + pos] = ((unsigned long long)key << 32) | (unsigned)a;
        }
      }
    }
  }
}

// ---------------- K6: rank-by-count + decode into rank-ordered arrays ----------------
__global__ __launch_bounds__(1024) void k_rank(const float* b0p, const float* b1p,
                                               const float* b2p, const float* b3p,
                                               const float* b4p,
                                               const unsigned long long* cand,
                                               const int* cnt,
                                               float4* iouA, float4* pout,
                                               float* sout, int* aout) {
  __shared__ unsigned long long sk[CAP];
  int b = blockIdx.x;
  int tid = threadIdx.x;
  int n = cnt[b]; if (n > CAP) n = CAP;
  for (int t = tid; t < CAP; t += 1024)
    sk[t] = (t < n) ? cand[(size_t)b * CAP + t] : ~0ull;
  __syncthreads();
  unsigned long long my0 = sk[tid], my1 = sk[tid + 1024];
  int r0 = 0, r1 = 0;
  #pragma unroll 4
  for (int j = 0; j < n; j++) {
    unsigned long long k = sk[j];
    r0 += (k < my0) ? 1 : 0;
    r1 += (k < my1) ? 1 : 0;
  }
  for (int pass = 0; pass < 2; pass++) {
    int slot = tid + pass * 1024;
    int r = pass == 0 ? r0 : r1;
    unsigned long long e = pass == 0 ? my0 : my1;
    if (slot < n && r < KTOP) {
      int a = (int)(unsigned)e;
      float sc = __uint_as_float(~(unsigned)(e >> 32));
      float x1, y1, x2, y2, cx, cy, wb, hb;
      decode_box(b0p, b1p, b2p, b3p, b4p, b, a, x1, y1, x2, y2, cx, cy, wb, hb);
      int o = b * KTOP + r;
      iouA[o] = make_float4(x1, y1, x2, y2);
      pout[o] = make_float4(cx, cy, wb, hb);
      sout[o] = sc;
      aout[o] = a;
    }
  }
}

// ---------------- K7: IoU bit-matrix ----------------
__global__ __launch_bounds__(1024) void k_iou(const float4* iouA,
                                              unsigned long long* gmask) {
  __shared__ float4 bx[KTOP];
  int b = blockIdx.y;
  int tid = threadIdx.x;
  if (tid < KTOP) bx[tid] = iouA[b * KTOP + tid];
  __syncthreads();
  int row = blockIdx.x * 64 + (tid >> 4);
  int cc = tid & 15;
  if (row >= KTOP) return;
  float4 rb = bx[row];
  float rar = (rb.z - rb.x) * (rb.w - rb.y);
  unsigned long long bits = 0;
  int cbase = cc * 64;
  #pragma unroll 4
  for (int c = 0; c < 64; c++) {
    int col = cbase + c;
    if (col < KTOP && col > row) {
      float4 cb4 = bx[col];
      float iw = fminf(rb.z, cb4.z) - fmaxf(rb.x, cb4.x); iw = fmaxf(iw, 0.f);
      float ih = fminf(rb.w, cb4.w) - fmaxf(rb.y, cb4.y); ih = fmaxf(ih, 0.f);
      float inter = iw * ih;
      float car = (cb4.z - cb4.x) * (cb4.w - cb4.y);
      float iou = inter / (rar + car - inter + 1e-6f);
      if (iou > NMS_T) bits |= (1ull << c);
    }
  }
  gmask[((size_t)b * KTOP + row) * 16 + cc] = bits;
}

// ---------------- K8: greedy resolve + scatter write ----------------
__global__ __launch_bounds__(1024) void k_greedy(const unsigned long long* gmask,
                                                 const float4* pout, const float* sout,
                                                 const int* aout,
                                                 float* out5, float* keepo) {
  __shared__ unsigned long long mrow[500 * 16];
  __shared__ unsigned long long kw[16];
  int b = blockIdx.x;
  int tid = threadIdx.x;
  unsigned long long rem = 0;
  int lane = tid & 63;
  for (int t = tid; t < 8000; t += 1024) mrow[t] = gmask[(size_t)b * 16000 + t];
  __syncthreads();
  if (tid < 64) {
    for (int i = 0; i < 500; i++) {
      unsigned long long rw = __shfl(rem, i >> 6, 64);
      if (!((rw >> (i & 63)) & 1) && lane < 16) rem |= mrow[i * 16 + lane];
    }
  }
  __syncthreads();
  for (int t = tid; t < 8000; t += 1024) mrow[t] = gmask[(size_t)b * 16000 + 8000 + t];
  __syncthreads();
  if (tid < 64) {
    for (int i = 500; i < KTOP; i++) {
      unsigned long long rw = __shfl(rem, i >> 6, 64);
      if (!((rw >> (i & 63)) & 1) && lane < 16) rem |= mrow[(i - 500) * 16 + lane];
    }
    if (lane < 16) kw[lane] = rem;
  }
  __syncthreads();
  if (tid < KTOP && !((kw[tid >> 6] >> (tid & 63)) & 1)) {
    int o = b * KTOP + tid;
    float4 pq = pout[o];
    float sc = sout[o];
    int a = aout[o];
    size_t p = (size_t)b * A_TOTAL + (size_t)a;
    float* op = out5 + p * 5;
    op[0] = pq.x; op[1] = pq.y; op[2] = pq.z; op[3] = pq.w; op[4] = sc;
    keepo[p] = 1.0f;
  }
}

// ======== fallback per-anchor path (round-2, proven) for small ws ========
__global__ __launch_bounds__(1024) void k_hist1_fb(const float* c0, const float* c1,
                                                   const float* c2, const float* c3,
                                                   const float* c4, int* coarse) {
  __shared__ int lh[256];
  int b = blockIdx.y;
  int tid = threadIdx.x;
  if (tid < 256) lh[tid] = 0;
  __syncthreads();
  int base = blockIdx.x * 32736;
  for (int it = 0; it < 32; it++) {
    int idx = it * 1024 + tid;
    if (idx < 32736) {
      float s = score_at(c0, c1, c2, c3, c4, b, base + idx);
      atomicAdd(&lh[bin_of(s) >> 6], 1);
    }
  }
  __syncthreads();
  if (tid < 256) {
    int v = lh[tid];
    if (v) atomicAdd(&coarse[b * 256 + tid], v);
  }
}

__global__ __launch_bounds__(1024) void k_hist2_fb(const float* c0, const float* c1,
                                                   const float* c2, const float* c3,
                                                   const float* c4, const int* cstar,
                                                   int* fine) {
  int b = blockIdx.y;
  int tid = threadIdx.x;
  int cs = cstar[b];
  int base = blockIdx.x * 32736;
  for (int it = 0; it < 32; it++) {
    int idx = it * 1024 + tid;
    if (idx < 32736) {
      float s = score_at(c0, c1, c2, c3, c4, b, base + idx);
      int bin = bin_of(s);
      if ((bin >> 6) == cs) atomicAdd(&fine[b * 64 + (bin & 63)], 1);
    }
  }
}

__global__ __launch_bounds__(1024) void k_compact_fb(const float* c0, const float* c1,
                                                     const float* c2, const float* c3,
                                                     const float* c4, const int* b0in,
                                                     int* cnt, unsigned long long* cand) {
  int b = blockIdx.y;
  int tid = threadIdx.x;
  int B0v = b0in[b];
  int base = blockIdx.x * 32736;
  for (int it = 0; it < 32; it++) {
    int idx = it * 1024 + tid;
    if (idx < 32736) {
      int a = base + idx;
      float s = score_at(c0, c1, c2, c3, c4, b, a);
      if (bin_of(s) >= B0v) {
        int pos = atomicAdd(&cnt[b], 1);
        if (pos < CAP) {
          unsigned key = ~__float_as_uint(s);
          cand[(size_t)b * CAP + pos] = ((unsigned long long)key << 32) | (unsigned)a;
        }
      }
    }
  }
}

__global__ __launch_bounds__(1024) void k_final_fb(const float* b0p, const float* b1p,
                                                   const float* b2p, const float* b3p,
                                                   const float* b4p,
                                                   const unsigned long long* cand,
                                                   const int* cnt,
                                                   float* out5, float* keepo) {
  __shared__ unsigned long long sk[CAP];
  __shared__ float sx1[KTOP], sy1[KTOP], sx2[KTOP], sy2[KTOP], sar[KTOP];
  __shared__ float scx[KTOP], scy[KTOP], swd[KTOP], sht[KTOP], ssc[KTOP];
  __shared__ int ssup[1024];
  int b = blockIdx.x;
  int tid = threadIdx.x;
  int n = cnt[b]; if (n > CAP) n = CAP;
  for (int t = tid; t < CAP; t += 1024)
    sk[t] = (t < n) ? cand[(size_t)b * CAP + t] : ~0ull;
  __syncthreads();
  for (int k = 2; k <= CAP; k <<= 1) {
    for (int j = k >> 1; j > 0; j >>= 1) {
      for (int i = tid; i < CAP; i += 1024) {
        int ixj = i ^ j;
        if (ixj > i) {
          bool up = ((i & k) == 0);
          unsigned long long v0 = sk[i], v1 = sk[ixj];
          if ((v0 > v1) == up) { sk[i] = v1; sk[ixj] = v0; }
        }
      }
      __syncthreads();
    }
  }
  if (tid < 1024) ssup[tid] = 1;
  if (tid < KTOP) {
    unsigned long long e = sk[tid];
    int a = (int)(unsigned)e;
    float sc = __uint_as_float(~(unsigned)(e >> 32));
    float x1, y1, x2, y2, cx, cy, wb, hb;
    decode_box(b0p, b1p, b2p, b3p, b4p, b, a, x1, y1, x2, y2, cx, cy, wb, hb);
    sx1[tid] = x1; sy1[tid] = y1; sx2[tid] = x2; sy2[tid] = y2;
    sar[tid] = (x2 - x1) * (y2 - y1);
    scx[tid] = cx; scy[tid] = cy; swd[tid] = wb; sht[tid] = hb; ssc[tid] = sc;
    ssup[tid] = 0;
  }
  __syncthreads();
  for (int c = 0; c < 16; c++) {
    int base = c * 64;
    if (tid < 64) {
      int j = base + tid;
      unsigned long long intra = 0;
      int sup;
      if (j < KTOP) {
        float x1 = sx1[j], y1 = sy1[j], x2 = sx2[j], y2 = sy2[j], ar = sar[j];
        for (int i2 = 0; i2 < 64; i2++) {
          int gi = base + i2;
          if (gi >= j) break;
          float iw = fminf(x2, sx2[gi]) - fmaxf(x1, sx1[gi]); iw = fmaxf(iw, 0.f);
          float ih = fminf(y2, sy2[gi]) - fmaxf(y1, sy1[gi]); ih = fmaxf(ih, 0.f);
          float inter = iw * ih;
          float iou = inter / (ar + sar[gi] - inter + 1e-6f);
          if (iou > NMS_T) intra |= (1ull << i2);
        }
        sup = ssup[j];
      } else sup = 1;
      for (int i2 = 0; i2 < 64; i2++) {
        int si = __shfl(sup, i2, 64);
        if (!si && ((intra >> i2) & 1)) sup = 1;
      }
      if (j < KTOP) ssup[j] = sup;
    }
    __syncthreads();
    int j2 = base + 64 + tid;
    if (j2 < KTOP && !ssup[j2]) {
      float x1 = sx1[j2], y1 = sy1[j2], x2 = sx2[j2], y2 = sy2[j2], ar = sar[j2];
      for (int i2 = 0; i2 < 64; i2++) {
        int gi = base + i2;
        if (!ssup[gi]) {
          float iw = fminf(x2, sx2[gi]) - fmaxf(x1, sx1[gi]); iw = fmaxf(iw, 0.f);
          float ih = fminf(y2, sy2[gi]) - fmaxf(y1, sy1[gi]); ih = fmaxf(ih, 0.f);
          float inter = iw * ih;
          float iou = inter / (ar + sar[gi] - inter + 1e-6f);
          if (iou > NMS_T) { ssup[j2] = 1; break; }
        }
      }
    }
    __syncthreads();
  }
  if (tid < KTOP && !ssup[tid]) {
    int a = (int)(unsigned)sk[tid];
    size_t p = (size_t)b * A_TOTAL + (size_t)a;
    size_t p5 = p * 5;
    out5[p5 + 0] = scx[tid];
    out5[p5 + 1] = scy[tid];
    out5[p5 + 2] = swd[tid];
    out5[p5 + 3] = sht[tid];
    out5[p5 + 4] = ssc[tid];
    keepo[p] = 1.0f;
  }
}

extern "C" void kernel_launch(void* const* d_in, const int* in_sizes, int n_in,
                              void* d_out, int out_size, void* d_ws, size_t ws_size,
                              hipStream_t stream) {
  const float *cls[5], *bbox[5];
  if (n_in >= 10 && in_sizes[1] == 4 * in_sizes[0]) {       // interleaved dict order
    for (int l = 0; l < 5; l++) { cls[l] = (const float*)d_in[2*l]; bbox[l] = (const float*)d_in[2*l+1]; }
  } else {                                                   // grouped order
    for (int l = 0; l < 5; l++) { cls[l] = (const float*)d_in[l]; bbox[l] = (const float*)d_in[5+l]; }
  }

  char* ws = (char*)d_ws;
  int* coarse = (int*)(ws + WS_COARSE);
  int* fine   = (int*)(ws + WS_FINE);
  int* cstar  = (int*)(ws + WS_CSTAR);
  int* sab    = (int*)(ws + WS_SAB);
  int* b0w    = (int*)(ws + WS_B0);
  int* cnt    = (int*)(ws + WS_CNT);
  unsigned long long* cand = (unsigned long long*)(ws + WS_CAND);
  float4* iouA = (float4*)(ws + WS_IOUA);
  float4* pout = (float4*)(ws + WS_POUT);
  float*  sout = (float*)(ws + WS_SOUT);
  int*    aout = (int*)(ws + WS_AOUT);
  unsigned long long* gmask = (unsigned long long*)(ws + WS_MASK);
  float4* sbuf = (float4*)(ws + WS_SCORES);

  float* out5  = (float*)d_out;
  float* keepo = out5 + (size_t)NBATCH * A_TOTAL * 5;

  k_zero<<<4096, 256, 0, stream>>>((float4*)d_out, (NBATCH * A_TOTAL * 6) / 4,
                                   (int*)ws, N_ZERO_INTS);

  bool have_scores = ws_size >= WS_NEED_SCORES;
  if (have_scores) {
    dim3 g64(64, NBATCH);
    k_score<<<g64, 256, 0, stream>>>(cls[0], cls[1], cls[2], cls[3], cls[4], sbuf, coarse);
    k_scan1<<<NBATCH, 256, 0, stream>>>(coarse, cstar, sab);
    k_fine<<<g64, 256, 0, stream>>>(sbuf, cstar, fine);
    k_scan2<<<NBATCH, 64, 0, stream>>>(fine, cstar, sab, b0w);
    k_compact<<<g64, 256, 0, stream>>>(sbuf, b0w, cnt, cand);
  } else {
    dim3 g8(8, NBATCH);
    k_hist1_fb<<<g8, 1024, 0, stream>>>(cls[0], cls[1], cls[2], cls[3], cls[4], coarse);
    k_scan1<<<NBATCH, 256, 0, stream>>>(coarse, cstar, sab);
    k_hist2_fb<<<g8, 1024, 0, stream>>>(cls[0], cls[1], cls[2], cls[3], cls[4], cstar, fine);
    k_scan2<<<NBATCH, 64, 0, stream>>>(fine, cstar, sab, b0w);
    k_compact_fb<<<g8, 1024, 0, stream>>>(cls[0], cls[1], cls[2], cls[3], cls[4], b0w, cnt, cand);
  }

  if (ws_size >= WS_NEED_FULL) {
    k_rank<<<NBATCH, 1024, 0, stream>>>(bbox[0], bbox[1], bbox[2], bbox[3], bbox[4],
                                        cand, cnt, iouA, pout, sout, aout);
    dim3 gi(16, NBATCH);
    k_iou<<<gi, 1024, 0, stream>>>(iouA, gmask);
    k_greedy<<<NBATCH, 1024, 0, stream>>>(gmask, pout, sout, aout, out5, keepo);
  } else {
    k_final_fb<<<NBATCH, 1024, 0, stream>>>(bbox[0], bbox[1], bbox[2], bbox[3], bbox[4],
                                            cand, cnt, out5, keepo);
  }
}

// Round 5
// 365.818 us; speedup vs baseline: 2.5587x; 1.4192x over previous
//
#include <hip/hip_runtime.h>
#include <cstdint>
#include <cstddef>

#define A_TOTAL 261888
#define NBATCH  16
#define KTOP    1000
#define CAP     2048
#define NMS_T   0.7f
#define F4_PER_IMG 65472          // 261888/4
#define F4_PER_BLK 1023           // 65472/64 blocks
#define STAGE_CAP 512             // per-block candidate staging (expected ~19, max ~45)

// ---- ws layout (bytes) ----
#define WS_HP    0                 // 16*64*256*4 = 1,048,576  coarse hist partials
#define WS_B0    1048576           // 16 ints
#define WS_CNT   1048640           // 16 ints (atomic accumulator -> zeroed in k_zero)
#define WS_CAND  1048704           // 16*2048*8   = 262,144
#define WS_IOUA  1310848           // 16*1000*16  = 256,000
#define WS_POUT  1566848           // 256,000
#define WS_SOUT  1822848           // 64,000
#define WS_AOUT  1886848           // 64,000
#define WS_MASK  1950848           // 16*1000*16*8 = 2,048,000 ; end = 3,998,848

__constant__ float c_stride[5] = {4.f, 8.f, 16.f, 32.f, 64.f};
__constant__ float c_aw[5][3] = {
  {(float)(32.0 /0.707106769084930419921875),  32.f, (float)(32.0 /1.41421353816986083984375)},
  {(float)(64.0 /0.707106769084930419921875),  64.f, (float)(64.0 /1.41421353816986083984375)},
  {(float)(128.0/0.707106769084930419921875), 128.f, (float)(128.0/1.41421353816986083984375)},
  {(float)(256.0/0.707106769084930419921875), 256.f, (float)(256.0/1.41421353816986083984375)},
  {(float)(512.0/0.707106769084930419921875), 512.f, (float)(512.0/1.41421353816986083984375)}};
__constant__ float c_ah[5][3] = {
  {(float)(32.0 *0.707106769084930419921875),  32.f, (float)(32.0 *1.41421353816986083984375)},
  {(float)(64.0 *0.707106769084930419921875),  64.f, (float)(64.0 *1.41421353816986083984375)},
  {(float)(128.0*0.707106769084930419921875), 128.f, (float)(128.0*1.41421353816986083984375)},
  {(float)(256.0*0.707106769084930419921875), 256.f, (float)(256.0*1.41421353816986083984375)},
  {(float)(512.0*0.707106769084930419921875), 512.f, (float)(512.0*1.41421353816986083984375)}};

__device__ __forceinline__ void decompA(int a, int& l, int& i) {
  if (a < 245760) {
    if (a < 196608) { l = 0; i = a; } else { l = 1; i = a - 196608; }
  } else if (a < 258048) { l = 2; i = a - 245760; }
  else if (a < 261120)   { l = 3; i = a - 258048; }
  else                   { l = 4; i = a - 261120; }
}

// element position e (per-image layout [level][r][pix]) -> level & within-level offset
__device__ __forceinline__ void decompE(int e, int& l, int& el) {
  if (e < 245760) {
    if (e < 196608) { l = 0; el = e; } else { l = 1; el = e - 196608; }
  } else if (e < 258048) { l = 2; el = e - 245760; }
  else if (e < 261120)   { l = 3; el = e - 258048; }
  else                   { l = 4; el = e - 261120; }
}

__device__ __forceinline__ int bin_of(float s) {
  int b = (int)(s * 16384.0f);
  return b > 16383 ? 16383 : (b < 0 ? 0 : b);
}

// layout-order float4 of sigmoid scores at float4-index f within image b
__device__ __forceinline__ float4 score4_at(const float* c0, const float* c1,
                                            const float* c2, const float* c3,
                                            const float* c4, int b, int f) {
  int l, off4;
  if (f < 49152) { l = 0; off4 = f; }
  else if (f < 61440) { l = 1; off4 = f - 49152; }
  else if (f < 64512) { l = 2; off4 = f - 61440; }
  else if (f < 65280) { l = 3; off4 = f - 64512; }
  else { l = 4; off4 = f - 65280; }
  int HW4x3 = 3 * (16384 >> (2 * l));  // 3*HW/4
  const float4* p = (const float4*)((l == 0) ? c0 : (l == 1) ? c1 : (l == 2) ? c2
                                     : (l == 3) ? c3 : c4);
  float4 x = p[(size_t)b * HW4x3 + off4];
  float4 s;
  s.x = 1.0f / (1.0f + expf(-x.x));
  s.y = 1.0f / (1.0f + expf(-x.y));
  s.z = 1.0f / (1.0f + expf(-x.z));
  s.w = 1.0f / (1.0f + expf(-x.w));
  return s;
}

__device__ __forceinline__ void decode_box(const float* b0p, const float* b1p,
                                           const float* b2p, const float* b3p,
                                           const float* b4p, int b, int a,
                                           float& x1, float& y1, float& x2, float& y2,
                                           float& cx, float& cy, float& wb, float& hb) {
  int l, i; decompA(a, l, i);
  unsigned pix = (unsigned)i / 3u;
  int r = i - (int)pix * 3;
  int W = 256 >> l;
  int HW = 65536 >> (2 * l);
  int hh_i = (int)pix >> (8 - l);
  int ww_i = (int)pix & (W - 1);
  const float* bp = (l == 0) ? b0p : (l == 1) ? b1p : (l == 2) ? b2p : (l == 3) ? b3p : b4p;
  size_t base = (size_t)(b * 12 + r * 4) * HW + (size_t)pix;
  float d0 = bp[base];
  float d1 = bp[base + HW];
  float d2 = bp[base + 2 * (size_t)HW];
  float d3 = bp[base + 3 * (size_t)HW];
  float stride = c_stride[l];
  float cxa = ((float)ww_i + 0.5f) * stride;
  float cya = ((float)hh_i + 0.5f) * stride;
  float aw = c_aw[l][r], ah = c_ah[l][r];
  cx = cxa + d0 * aw;
  cy = cya + d1 * ah;
  wb = aw * expf(fminf(fmaxf(d2, -4.f), 4.f));
  hb = ah * expf(fminf(fmaxf(d3, -4.f), 4.f));
  x1 = cx - wb * 0.5f; x2 = cx + wb * 0.5f;
  y1 = cy - hb * 0.5f; y2 = cy + hb * 0.5f;
}

// ---------------- K0: zero output + cnt accumulators ----------------
__global__ __launch_bounds__(256) void k_zero(float4* o, int n4, int* m, int nm) {
  int stride = gridDim.x * blockDim.x;
  int t = blockIdx.x * blockDim.x + threadIdx.x;
  float4 z = make_float4(0.f, 0.f, 0.f, 0.f);
  for (int i = t; i < n4; i += stride) o[i] = z;
  for (int i = t; i < nm; i += stride) m[i] = 0;
}

// ---------------- K1: coarse histogram partials (no global atomics) ----------------
__global__ __launch_bounds__(256) void k_hist(const float* c0, const float* c1,
                                              const float* c2, const float* c3,
                                              const float* c4, int* hp) {
  __shared__ int lh[256];
  int b = blockIdx.y, blk = blockIdx.x, tid = threadIdx.x;
  lh[tid] = 0;
  __syncthreads();
  int f0 = blk * F4_PER_BLK;
  #pragma unroll
  for (int it = 0; it < 4; it++) {
    int f = f0 + it * 256 + tid;
    if (f < f0 + F4_PER_BLK) {
      float4 s = score4_at(c0, c1, c2, c3, c4, b, f);
      atomicAdd(&lh[bin_of(s.x) >> 6], 1);
      atomicAdd(&lh[bin_of(s.y) >> 6], 1);
      atomicAdd(&lh[bin_of(s.z) >> 6], 1);
      atomicAdd(&lh[bin_of(s.w) >> 6], 1);
    }
  }
  __syncthreads();
  hp[(size_t)(b * 64 + blk) * 256 + tid] = lh[tid];
}

// ---------------- K2: reduce partials, coarse crossing -> superset threshold ----------------
__global__ __launch_bounds__(256) void k_scan1(const int* hp, int* b0c) {
  __shared__ int ch[256];
  int b = blockIdx.x, t = threadIdx.x;
  int s = 0;
  for (int blk = 0; blk < 64; blk++) s += hp[(size_t)(b * 64 + blk) * 256 + t];
  ch[t] = s;
  __syncthreads();
  if (t == 0) {
    int acc = 0, cs = 0;
    for (int cb = 255; cb >= 0; cb--) {
      if (acc + ch[cb] >= KTOP) { cs = cb; break; }
      acc += ch[cb];
    }
    b0c[b] = cs * 64;   // superset threshold; exact top-K recovered by ranking
  }
}

// ---------------- K3: compact superset candidates ----------------
// LDS staging + ONE global atomic reserve per block (content-deterministic,
// order-independent -> downstream exact ranking makes output deterministic).
__global__ __launch_bounds__(256) void k_compact(const float* c0, const float* c1,
                                                 const float* c2, const float* c3,
                                                 const float* c4, const int* b0c,
                                                 int* cnt, unsigned long long* cand) {
  __shared__ unsigned long long stage[STAGE_CAP];
  __shared__ int lc, gbase;
  int b = blockIdx.y, blk = blockIdx.x, tid = threadIdx.x;
  if (tid == 0) lc = 0;
  __syncthreads();
  int B0v = b0c[b];
  int f0 = blk * F4_PER_BLK;
  #pragma unroll
  for (int it = 0; it < 4; it++) {
    int f = f0 + it * 256 + tid;
    if (f < f0 + F4_PER_BLK) {
      float4 s = score4_at(c0, c1, c2, c3, c4, b, f);
      float sv[4] = {s.x, s.y, s.z, s.w};
      #pragma unroll
      for (int j = 0; j < 4; j++) {
        if (bin_of(sv[j]) >= B0v) {
          int e = f * 4 + j;
          int l, el; decompE(e, l, el);
          int shift = 16 - 2 * l;
          int r = el >> shift;
          int pix = el & ((1 << shift) - 1);
          int a = (e - el) + pix * 3 + r;
          int pos = atomicAdd(&lc, 1);
          if (pos < STAGE_CAP) {
            unsigned key = ~__float_as_uint(sv[j]);
            stage[pos] = ((unsigned long long)key << 32) | (unsigned)a;
          }
        }
      }
    }
  }
  __syncthreads();
  if (tid == 0) {
    int c = lc; if (c > STAGE_CAP) c = STAGE_CAP;
    lc = c;
    gbase = atomicAdd(&cnt[b], c);
  }
  __syncthreads();
  int c = lc, g0 = gbase;
  for (int t = tid; t < c; t += 256) {
    int gp = g0 + t;
    if (gp < CAP) cand[(size_t)b * CAP + gp] = stage[t];
  }
}

// ---------------- K4: exact rank-by-count + decode into rank-ordered arrays ----------------
__global__ __launch_bounds__(1024) void k_rank(const float* b0p, const float* b1p,
                                               const float* b2p, const float* b3p,
                                               const float* b4p,
                                               const unsigned long long* cand,
                                               const int* cnt,
                                               float4* iouA, float4* pout,
                                               float* sout, int* aout) {
  __shared__ unsigned long long sk[CAP];
  int b = blockIdx.x;
  int tid = threadIdx.x;
  int n = cnt[b]; if (n > CAP) n = CAP;
  for (int t = tid; t < CAP; t += 1024)
    sk[t] = (t < n) ? cand[(size_t)b * CAP + t] : ~0ull;
  __syncthreads();
  unsigned long long my0 = sk[tid], my1 = sk[tid + 1024];
  int r0 = 0, r1 = 0;
  #pragma unroll 4
  for (int j = 0; j < n; j++) {
    unsigned long long k = sk[j];
    r0 += (k < my0) ? 1 : 0;
    r1 += (k < my1) ? 1 : 0;
  }
  #pragma unroll
  for (int pass = 0; pass < 2; pass++) {
    int slot = tid + pass * 1024;
    int r = pass == 0 ? r0 : r1;
    unsigned long long e = pass == 0 ? my0 : my1;
    if (slot < n && r < KTOP) {
      int a = (int)(unsigned)e;
      float sc = __uint_as_float(~(unsigned)(e >> 32));
      float x1, y1, x2, y2, cx, cy, wb, hb;
      decode_box(b0p, b1p, b2p, b3p, b4p, b, a, x1, y1, x2, y2, cx, cy, wb, hb);
      int o = b * KTOP + r;
      iouA[o] = make_float4(x1, y1, x2, y2);
      pout[o] = make_float4(cx, cy, wb, hb);
      sout[o] = sc;
      aout[o] = a;
    }
  }
}

// ---------------- K5: IoU bit-matrix ----------------
__global__ __launch_bounds__(1024) void k_iou(const float4* iouA,
                                              unsigned long long* gmask) {
  __shared__ float4 bx[KTOP];
  int b = blockIdx.y;
  int tid = threadIdx.x;
  if (tid < KTOP) bx[tid] = iouA[b * KTOP + tid];
  __syncthreads();
  int row = blockIdx.x * 64 + (tid >> 4);
  int cc = tid & 15;
  if (row >= KTOP) return;
  float4 rb = bx[row];
  float rar = (rb.z - rb.x) * (rb.w - rb.y);
  unsigned long long bits = 0;
  int cbase = cc * 64;
  #pragma unroll 4
  for (int c = 0; c < 64; c++) {
    int col = cbase + c;
    if (col < KTOP && col > row) {
      float4 cb4 = bx[col];
      float iw = fminf(rb.z, cb4.z) - fmaxf(rb.x, cb4.x); iw = fmaxf(iw, 0.f);
      float ih = fminf(rb.w, cb4.w) - fmaxf(rb.y, cb4.y); ih = fmaxf(ih, 0.f);
      float inter = iw * ih;
      float car = (cb4.z - cb4.x) * (cb4.w - cb4.y);
      float iou = inter / (rar + car - inter + 1e-6f);
      if (iou > NMS_T) bits |= (1ull << c);
    }
  }
  gmask[((size_t)b * KTOP + row) * 16 + cc] = bits;
}

// ---------------- K6: greedy resolve + scatter write ----------------
__global__ __launch_bounds__(1024) void k_greedy(const unsigned long long* gmask,
                                                 const float4* pout, const float* sout,
                                                 const int* aout,
                                                 float* out5, float* keepo) {
  __shared__ unsigned long long mrow[500 * 16];
  __shared__ unsigned long long kw[16];
  int b = blockIdx.x;
  int tid = threadIdx.x;
  unsigned long long rem = 0;
  int lane = tid & 63;
  for (int t = tid; t < 8000; t += 1024) mrow[t] = gmask[(size_t)b * 16000 + t];
  __syncthreads();
  if (tid < 64) {
    for (int i = 0; i < 500; i++) {
      unsigned long long rw = __shfl(rem, i >> 6, 64);
      if (!((rw >> (i & 63)) & 1) && lane < 16) rem |= mrow[i * 16 + lane];
    }
  }
  __syncthreads();
  for (int t = tid; t < 8000; t += 1024) mrow[t] = gmask[(size_t)b * 16000 + 8000 + t];
  __syncthreads();
  if (tid < 64) {
    for (int i = 500; i < KTOP; i++) {
      unsigned long long rw = __shfl(rem, i >> 6, 64);
      if (!((rw >> (i & 63)) & 1) && lane < 16) rem |= mrow[(i - 500) * 16 + lane];
    }
    if (lane < 16) kw[lane] = rem;
  }
  __syncthreads();
  if (tid < KTOP && !((kw[tid >> 6] >> (tid & 63)) & 1)) {
    int o = b * KTOP + tid;
    float4 pq = pout[o];
    float sc = sout[o];
    int a = aout[o];
    size_t p = (size_t)b * A_TOTAL + (size_t)a;
    float* op = out5 + p * 5;
    op[0] = pq.x; op[1] = pq.y; op[2] = pq.z; op[3] = pq.w; op[4] = sc;
    keepo[p] = 1.0f;
  }
}

extern "C" void kernel_launch(void* const* d_in, const int* in_sizes, int n_in,
                              void* d_out, int out_size, void* d_ws, size_t ws_size,
                              hipStream_t stream) {
  const float *cls[5], *bbox[5];
  if (n_in >= 10 && in_sizes[1] == 4 * in_sizes[0]) {       // interleaved dict order
    for (int l = 0; l < 5; l++) { cls[l] = (const float*)d_in[2*l]; bbox[l] = (const float*)d_in[2*l+1]; }
  } else {                                                   // grouped order
    for (int l = 0; l < 5; l++) { cls[l] = (const float*)d_in[l]; bbox[l] = (const float*)d_in[5+l]; }
  }

  char* ws = (char*)d_ws;
  int* hp     = (int*)(ws + WS_HP);
  int* b0c    = (int*)(ws + WS_B0);
  int* cnt    = (int*)(ws + WS_CNT);
  unsigned long long* cand = (unsigned long long*)(ws + WS_CAND);
  float4* iouA = (float4*)(ws + WS_IOUA);
  float4* pout = (float4*)(ws + WS_POUT);
  float*  sout = (float*)(ws + WS_SOUT);
  int*    aout = (int*)(ws + WS_AOUT);
  unsigned long long* gmask = (unsigned long long*)(ws + WS_MASK);

  float* out5  = (float*)d_out;
  float* keepo = out5 + (size_t)NBATCH * A_TOTAL * 5;

  k_zero<<<4096, 256, 0, stream>>>((float4*)d_out, (NBATCH * A_TOTAL * 6) / 4,
                                   cnt, NBATCH);

  dim3 g64(64, NBATCH);
  k_hist<<<g64, 256, 0, stream>>>(cls[0], cls[1], cls[2], cls[3], cls[4], hp);
  k_scan1<<<NBATCH, 256, 0, stream>>>(hp, b0c);
  k_compact<<<g64, 256, 0, stream>>>(cls[0], cls[1], cls[2], cls[3], cls[4], b0c, cnt, cand);

  k_rank<<<NBATCH, 1024, 0, stream>>>(bbox[0], bbox[1], bbox[2], bbox[3], bbox[4],
                                      cand, cnt, iouA, pout, sout, aout);
  dim3 gi(16, NBATCH);
  k_iou<<<gi, 1024, 0, stream>>>(iouA, gmask);
  k_greedy<<<NBATCH, 1024, 0, stream>>>(gmask, pout, sout, aout, out5, keepo);
}

// Round 6
// 335.642 us; speedup vs baseline: 2.7887x; 1.0899x over previous
//
#include <hip/hip_runtime.h>
#include <cstdint>
#include <cstddef>

#define A_TOTAL 261888
#define NBATCH  16
#define KTOP    1000
#define CAP     2048
#define NMS_T   0.7f
#define F4_PER_IMG 65472          // 261888/4
#define F4_PER_BLK 1023           // 65472/64 blocks
#define STAGE_CAP 512             // per-block candidate staging (expected ~19)

// ---- ws layout (bytes) ----
#define WS_HP    0                 // 16*64*256*4 = 1,048,576  coarse hist partials
#define WS_CNT   1048640           // 16 ints (atomic accumulator -> zeroed in k_init)
#define WS_CAND  1048704           // 16*2048*8   = 262,144
#define WS_IOUA  1310848           // 16*1000*16  = 256,000
#define WS_POUT  1566848           // 256,000
#define WS_SOUT  1822848           // 64,000
#define WS_AOUT  1886848           // 64,000
#define WS_MASK  1950848           // 16*16*1000*8 = 2,048,000 ; end = 3,998,848

__constant__ float c_stride[5] = {4.f, 8.f, 16.f, 32.f, 64.f};
__constant__ float c_aw[5][3] = {
  {(float)(32.0 /0.707106769084930419921875),  32.f, (float)(32.0 /1.41421353816986083984375)},
  {(float)(64.0 /0.707106769084930419921875),  64.f, (float)(64.0 /1.41421353816986083984375)},
  {(float)(128.0/0.707106769084930419921875), 128.f, (float)(128.0/1.41421353816986083984375)},
  {(float)(256.0/0.707106769084930419921875), 256.f, (float)(256.0/1.41421353816986083984375)},
  {(float)(512.0/0.707106769084930419921875), 512.f, (float)(512.0/1.41421353816986083984375)}};
__constant__ float c_ah[5][3] = {
  {(float)(32.0 *0.707106769084930419921875),  32.f, (float)(32.0 *1.41421353816986083984375)},
  {(float)(64.0 *0.707106769084930419921875),  64.f, (float)(64.0 *1.41421353816986083984375)},
  {(float)(128.0*0.707106769084930419921875), 128.f, (float)(128.0*1.41421353816986083984375)},
  {(float)(256.0*0.707106769084930419921875), 256.f, (float)(256.0*1.41421353816986083984375)},
  {(float)(512.0*0.707106769084930419921875), 512.f, (float)(512.0*1.41421353816986083984375)}};

__device__ __forceinline__ void decompA(int a, int& l, int& i) {
  if (a < 245760) {
    if (a < 196608) { l = 0; i = a; } else { l = 1; i = a - 196608; }
  } else if (a < 258048) { l = 2; i = a - 245760; }
  else if (a < 261120)   { l = 3; i = a - 258048; }
  else                   { l = 4; i = a - 261120; }
}

__device__ __forceinline__ void decompE(int e, int& l, int& el) {
  if (e < 245760) {
    if (e < 196608) { l = 0; el = e; } else { l = 1; el = e - 196608; }
  } else if (e < 258048) { l = 2; el = e - 245760; }
  else if (e < 261120)   { l = 3; el = e - 258048; }
  else                   { l = 4; el = e - 261120; }
}

__device__ __forceinline__ int bin_of(float s) {
  int b = (int)(s * 16384.0f);
  return b > 16383 ? 16383 : (b < 0 ? 0 : b);
}

__device__ __forceinline__ float4 score4_at(const float* c0, const float* c1,
                                            const float* c2, const float* c3,
                                            const float* c4, int b, int f) {
  int l, off4;
  if (f < 49152) { l = 0; off4 = f; }
  else if (f < 61440) { l = 1; off4 = f - 49152; }
  else if (f < 64512) { l = 2; off4 = f - 61440; }
  else if (f < 65280) { l = 3; off4 = f - 64512; }
  else { l = 4; off4 = f - 65280; }
  int HW4x3 = 3 * (16384 >> (2 * l));
  const float4* p = (const float4*)((l == 0) ? c0 : (l == 1) ? c1 : (l == 2) ? c2
                                     : (l == 3) ? c3 : c4);
  float4 x = p[(size_t)b * HW4x3 + off4];
  float4 s;
  s.x = 1.0f / (1.0f + expf(-x.x));
  s.y = 1.0f / (1.0f + expf(-x.y));
  s.z = 1.0f / (1.0f + expf(-x.z));
  s.w = 1.0f / (1.0f + expf(-x.w));
  return s;
}

__device__ __forceinline__ void decode_box(const float* b0p, const float* b1p,
                                           const float* b2p, const float* b3p,
                                           const float* b4p, int b, int a,
                                           float& x1, float& y1, float& x2, float& y2,
                                           float& cx, float& cy, float& wb, float& hb) {
  int l, i; decompA(a, l, i);
  unsigned pix = (unsigned)i / 3u;
  int r = i - (int)pix * 3;
  int W = 256 >> l;
  int HW = 65536 >> (2 * l);
  int hh_i = (int)pix >> (8 - l);
  int ww_i = (int)pix & (W - 1);
  const float* bp = (l == 0) ? b0p : (l == 1) ? b1p : (l == 2) ? b2p : (l == 3) ? b3p : b4p;
  size_t base = (size_t)(b * 12 + r * 4) * HW + (size_t)pix;
  float d0 = bp[base];
  float d1 = bp[base + HW];
  float d2 = bp[base + 2 * (size_t)HW];
  float d3 = bp[base + 3 * (size_t)HW];
  float stride = c_stride[l];
  float cxa = ((float)ww_i + 0.5f) * stride;
  float cya = ((float)hh_i + 0.5f) * stride;
  float aw = c_aw[l][r], ah = c_ah[l][r];
  cx = cxa + d0 * aw;
  cy = cya + d1 * ah;
  wb = aw * expf(fminf(fmaxf(d2, -4.f), 4.f));
  hb = ah * expf(fminf(fmaxf(d3, -4.f), 4.f));
  x1 = cx - wb * 0.5f; x2 = cx + wb * 0.5f;
  y1 = cy - hb * 0.5f; y2 = cy + hb * 0.5f;
}

// ---------------- K1: zero output + cnt  AND  coarse histogram partials ----------------
__global__ __launch_bounds__(256) void k_init(const float* c0, const float* c1,
                                              const float* c2, const float* c3,
                                              const float* c4,
                                              float4* o, int n4, int* cnt, int* hp) {
  __shared__ int lh[256];
  int bx = blockIdx.x, tid = threadIdx.x;
  // zero output (all 4096 blocks, grid-stride)
  int gstride = gridDim.x * 256;
  float4 z = make_float4(0.f, 0.f, 0.f, 0.f);
  for (int i = bx * 256 + tid; i < n4; i += gstride) o[i] = z;
  if (bx == 0 && tid < NBATCH) cnt[tid] = 0;
  // histogram (first 1024 blocks)
  if (bx < 1024) {
    lh[tid] = 0;
    __syncthreads();
    int b = bx >> 6, blk = bx & 63;
    int f0 = blk * F4_PER_BLK;
    #pragma unroll
    for (int it = 0; it < 4; it++) {
      int f = f0 + it * 256 + tid;
      if (f < f0 + F4_PER_BLK) {
        float4 s = score4_at(c0, c1, c2, c3, c4, b, f);
        atomicAdd(&lh[bin_of(s.x) >> 6], 1);
        atomicAdd(&lh[bin_of(s.y) >> 6], 1);
        atomicAdd(&lh[bin_of(s.z) >> 6], 1);
        atomicAdd(&lh[bin_of(s.w) >> 6], 1);
      }
    }
    __syncthreads();
    hp[(size_t)(b * 64 + blk) * 256 + tid] = lh[tid];
  }
}

// ---------------- K2: threshold (folded) + compact superset candidates ----------------
__global__ __launch_bounds__(256) void k_compact(const float* c0, const float* c1,
                                                 const float* c2, const float* c3,
                                                 const float* c4, const int* hp,
                                                 int* cnt, unsigned long long* cand) {
  __shared__ int ch[256];
  __shared__ unsigned long long stage[STAGE_CAP];
  __shared__ int b0s, lc, gbase;
  int b = blockIdx.y, blk = blockIdx.x, tid = threadIdx.x;
  // reduce partials for image b (redundant per block; L2-resident, ~17 scan iters)
  int s = 0;
  for (int k = 0; k < 64; k++) s += hp[(size_t)(b * 64 + k) * 256 + tid];
  ch[tid] = s;
  if (tid == 0) lc = 0;
  __syncthreads();
  if (tid == 0) {
    int acc = 0, cs = 0;
    for (int cb = 255; cb >= 0; cb--) {
      if (acc + ch[cb] >= KTOP) { cs = cb; break; }
      acc += ch[cb];
    }
    b0s = cs * 64;   // superset threshold; exact top-K recovered by ranking
  }
  __syncthreads();
  int B0v = b0s;
  int f0 = blk * F4_PER_BLK;
  #pragma unroll
  for (int it = 0; it < 4; it++) {
    int f = f0 + it * 256 + tid;
    if (f < f0 + F4_PER_BLK) {
      float4 sc4 = score4_at(c0, c1, c2, c3, c4, b, f);
      float sv[4] = {sc4.x, sc4.y, sc4.z, sc4.w};
      #pragma unroll
      for (int j = 0; j < 4; j++) {
        if (bin_of(sv[j]) >= B0v) {
          int e = f * 4 + j;
          int l, el; decompE(e, l, el);
          int shift = 16 - 2 * l;
          int r = el >> shift;
          int pix = el & ((1 << shift) - 1);
          int a = (e - el) + pix * 3 + r;
          int pos = atomicAdd(&lc, 1);
          if (pos < STAGE_CAP) {
            unsigned key = ~__float_as_uint(sv[j]);
            stage[pos] = ((unsigned long long)key << 32) | (unsigned)a;
          }
        }
      }
    }
  }
  __syncthreads();
  if (tid == 0) {
    int c = lc; if (c > STAGE_CAP) c = STAGE_CAP;
    lc = c;
    gbase = atomicAdd(&cnt[b], c);
  }
  __syncthreads();
  int c = lc, g0 = gbase;
  for (int t = tid; t < c; t += 256) {
    int gp = g0 + t;
    if (gp < CAP) cand[(size_t)b * CAP + gp] = stage[t];
  }
}

// ---------------- K3: exact rank-by-count + decode (1 wave/block, 128 slots) ----------------
__global__ __launch_bounds__(64) void k_rank(const float* b0p, const float* b1p,
                                             const float* b2p, const float* b3p,
                                             const float* b4p,
                                             const unsigned long long* cand,
                                             const int* cnt,
                                             float4* iouA, float4* pout,
                                             float* sout, int* aout) {
  __shared__ unsigned long long sk[CAP];
  int b = blockIdx.y, g = blockIdx.x;
  int lane = threadIdx.x;
  int n = cnt[b]; if (n > CAP) n = CAP;
  for (int t = lane; t < CAP; t += 64)
    sk[t] = (t < n) ? cand[(size_t)b * CAP + t] : ~0ull;
  __syncthreads();
  int s0 = g * 128 + lane, s1 = s0 + 64;
  unsigned long long my0 = sk[s0], my1 = sk[s1];
  int r0 = 0, r1 = 0;
  #pragma unroll 4
  for (int j = 0; j < n; j++) {
    unsigned long long k = sk[j];
    r0 += (k < my0) ? 1 : 0;
    r1 += (k < my1) ? 1 : 0;
  }
  #pragma unroll
  for (int pass = 0; pass < 2; pass++) {
    int slot = pass == 0 ? s0 : s1;
    int r = pass == 0 ? r0 : r1;
    unsigned long long e = pass == 0 ? my0 : my1;
    if (slot < n && r < KTOP) {
      int a = (int)(unsigned)e;
      float sc = __uint_as_float(~(unsigned)(e >> 32));
      float x1, y1, x2, y2, cx, cy, wb, hb;
      decode_box(b0p, b1p, b2p, b3p, b4p, b, a, x1, y1, x2, y2, cx, cy, wb, hb);
      int o = b * KTOP + r;
      iouA[o] = make_float4(x1, y1, x2, y2);
      pout[o] = make_float4(cx, cy, wb, hb);
      sout[o] = sc;
      aout[o] = a;
    }
  }
}

// ---------------- K4: FULL symmetric IoU bit-matrix, transposed layout ----------------
// gmaskT[(b*16 + word)*KTOP + row] bit c set iff col=word*64+c != row, col<KTOP, IoU>thr
__global__ __launch_bounds__(1024) void k_iou(const float4* iouA,
                                              unsigned long long* gmaskT) {
  __shared__ float4 bx[KTOP];
  int b = blockIdx.y;
  int tid = threadIdx.x;
  if (tid < KTOP) bx[tid] = iouA[b * KTOP + tid];
  __syncthreads();
  int row = blockIdx.x * 64 + (tid >> 4);
  int cc = tid & 15;
  if (row >= KTOP) return;
  float4 rb = bx[row];
  float rar = (rb.z - rb.x) * (rb.w - rb.y);
  unsigned long long bits = 0;
  int cbase = cc * 64;
  #pragma unroll 4
  for (int c = 0; c < 64; c++) {
    int col = cbase + c;
    if (col < KTOP && col != row) {
      float4 cb4 = bx[col];
      float iw = fminf(rb.z, cb4.z) - fmaxf(rb.x, cb4.x); iw = fmaxf(iw, 0.f);
      float ih = fminf(rb.w, cb4.w) - fmaxf(rb.y, cb4.y); ih = fmaxf(ih, 0.f);
      float inter = iw * ih;
      float car = (cb4.z - cb4.x) * (cb4.w - cb4.y);
      float iou = inter / (rar + car - inter + 1e-6f);
      if (iou > NMS_T) bits |= (1ull << c);
    }
  }
  gmaskT[((size_t)b * 16 + cc) * KTOP + row] = bits;
}

// ---------------- K5: ballot-greedy resolve + scatter write ----------------
__global__ __launch_bounds__(1024) void k_greedy(const unsigned long long* gmaskT,
                                                 const float4* pout, const float* sout,
                                                 const int* aout,
                                                 float* out5, float* keepo) {
  __shared__ unsigned long long rem[16];
  __shared__ unsigned long long kept64[16];
  int b = blockIdx.x;
  int tid = threadIdx.x;
  if (tid < 16) rem[tid] = 0ull;
  __syncthreads();
  for (int c = 0; c < 16; c++) {
    // phase A: wave 0 resolves chunk c greedily via ballot (no memory in chain)
    if (tid < 64) {
      int j = tid;
      int row = c * 64 + j;
      unsigned long long w = 0ull;
      int sup = 1;
      if (row < KTOP) {
        w = gmaskT[((size_t)b * 16 + c) * KTOP + row];  // intra-chunk column word
        sup = (int)((rem[c] >> j) & 1ull);
      }
      for (int i = 0; i < 64; i++) {
        unsigned long long bal = __ballot(sup == 0);    // current keep vector
        if (j > i && ((bal >> i) & 1ull) && ((w >> i) & 1ull)) sup = 1;
      }
      unsigned long long km = __ballot(sup == 0);
      if (j == 0) kept64[c] = km;
    }
    __syncthreads();
    // phase B: 16 waves OR kept rows' suppression words into rem
    {
      int wv = tid >> 6, i = tid & 63;
      unsigned long long km = kept64[c];
      int row = c * 64 + i;
      unsigned long long v = 0ull;
      if (row < KTOP && ((km >> i) & 1ull))
        v = gmaskT[((size_t)b * 16 + wv) * KTOP + row];
      for (int o = 32; o > 0; o >>= 1) v |= __shfl_xor(v, o, 64);
      if (i == 0) rem[wv] |= v;
    }
    __syncthreads();
  }
  if (tid < KTOP && ((kept64[tid >> 6] >> (tid & 63)) & 1ull)) {
    int o = b * KTOP + tid;
    float4 pq = pout[o];
    float sc = sout[o];
    int a = aout[o];
    size_t p = (size_t)b * A_TOTAL + (size_t)a;
    float* op = out5 + p * 5;
    op[0] = pq.x; op[1] = pq.y; op[2] = pq.z; op[3] = pq.w; op[4] = sc;
    keepo[p] = 1.0f;
  }
}

extern "C" void kernel_launch(void* const* d_in, const int* in_sizes, int n_in,
                              void* d_out, int out_size, void* d_ws, size_t ws_size,
                              hipStream_t stream) {
  const float *cls[5], *bbox[5];
  if (n_in >= 10 && in_sizes[1] == 4 * in_sizes[0]) {       // interleaved dict order
    for (int l = 0; l < 5; l++) { cls[l] = (const float*)d_in[2*l]; bbox[l] = (const float*)d_in[2*l+1]; }
  } else {                                                   // grouped order
    for (int l = 0; l < 5; l++) { cls[l] = (const float*)d_in[l]; bbox[l] = (const float*)d_in[5+l]; }
  }

  char* ws = (char*)d_ws;
  int* hp     = (int*)(ws + WS_HP);
  int* cnt    = (int*)(ws + WS_CNT);
  unsigned long long* cand = (unsigned long long*)(ws + WS_CAND);
  float4* iouA = (float4*)(ws + WS_IOUA);
  float4* pout = (float4*)(ws + WS_POUT);
  float*  sout = (float*)(ws + WS_SOUT);
  int*    aout = (int*)(ws + WS_AOUT);
  unsigned long long* gmaskT = (unsigned long long*)(ws + WS_MASK);

  float* out5  = (float*)d_out;
  float* keepo = out5 + (size_t)NBATCH * A_TOTAL * 5;

  k_init<<<4096, 256, 0, stream>>>(cls[0], cls[1], cls[2], cls[3], cls[4],
                                   (float4*)d_out, (NBATCH * A_TOTAL * 6) / 4,
                                   cnt, hp);
  dim3 g64(64, NBATCH);
  k_compact<<<g64, 256, 0, stream>>>(cls[0], cls[1], cls[2], cls[3], cls[4],
                                     hp, cnt, cand);
  dim3 gr(16, NBATCH);
  k_rank<<<gr, 64, 0, stream>>>(bbox[0], bbox[1], bbox[2], bbox[3], bbox[4],
                                cand, cnt, iouA, pout, sout, aout);
  dim3 gi(16, NBATCH);
  k_iou<<<gi, 1024, 0, stream>>>(iouA, gmaskT);
  k_greedy<<<NBATCH, 1024, 0, stream>>>(gmaskT, pout, sout, aout, out5, keepo);
}